// Round 7
// baseline (450.153 us; speedup 1.0000x reference)
//
#include <hip/hip_runtime.h>
#include <hip/hip_bf16.h>

typedef __hip_bfloat16 bf16;
typedef __attribute__((ext_vector_type(8))) short short8;
typedef __attribute__((ext_vector_type(4))) float floatx4;

// Problem constants: B=4, S=1024, M=8, D=64, H=8, NF=32, HD=512
#define CB 4
#define CS 1024
#define CM 8
#define CD 64
#define CH 8
#define CNF 32
#define CHD 512

#define SC_STRIDE 520    // attn score-row stride in shorts: 512 cols + 8 pad
                         // (260 words, 260%32=4 -> <=2-way bank aliasing; rows 16B-aligned)
#define OS_STRIDE 68     // finalize staging stride (fp32)

__device__ __forceinline__ float b2f(bf16 x) { return __bfloat162float(x); }
__device__ __forceinline__ float us2f(unsigned short u) {
    union { unsigned int i; float f; } v; v.i = ((unsigned int)u) << 16; return v.f;
}
__device__ __forceinline__ floatx4 mfma16(short8 a, short8 b, floatx4 c) {
    return __builtin_amdgcn_mfma_f32_16x16x32_bf16(a, b, c, 0, 0, 0);
}
__device__ __forceinline__ short8 pack8(float4 x, float4 y) {
    union { short8 s; bf16 b[8]; } u;
    u.b[0] = __float2bfloat16(x.x); u.b[1] = __float2bfloat16(x.y);
    u.b[2] = __float2bfloat16(x.z); u.b[3] = __float2bfloat16(x.w);
    u.b[4] = __float2bfloat16(y.x); u.b[5] = __float2bfloat16(y.y);
    u.b[6] = __float2bfloat16(y.z); u.b[7] = __float2bfloat16(y.w);
    return u.s;
}

// ---------------------------------------------------------------------------
// Kernel 1: Fb[which][n=h*32+f][e] (bf16, n-major MFMA B-layout)
//   = sum_d W[h*64+d][e] * freqs[h][d][f];  + convert Wo -> bf16.
// ---------------------------------------------------------------------------
__global__ __launch_bounds__(256) void prep_F(const float* __restrict__ Wq,
                                              const float* __restrict__ Wk,
                                              const float* __restrict__ freqs,
                                              const float* __restrict__ Wo,
                                              bf16* __restrict__ Fqb,
                                              bf16* __restrict__ Fkb,
                                              bf16* __restrict__ Wo_bf) {
    int h = blockIdx.x & 7;
    int which = blockIdx.x >> 3;
    const float* W = which ? Wk : Wq;
    bf16* Fb = which ? Fkb : Fqb;
    int t = threadIdx.x;
    int f = t & 31, e0 = t >> 5;
    for (int ei = 0; ei < 8; ++ei) {
        int e = ei * 8 + e0;
        float acc = 0.f;
        for (int d = 0; d < 64; ++d)
            acc += W[(h * 64 + d) * 64 + e] * freqs[(h * 64 + d) * 32 + f];
        Fb[(h * 32 + f) * 64 + e] = __float2bfloat16(acc);
    }
    int gid = blockIdx.x * 256 + t;
    #pragma unroll
    for (int i = 0; i < 2; ++i) {
        int idx4 = gid * 2 + i;
        float4 v = ((const float4*)Wo)[idx4];
        union { bf16 ob[4]; uint2 u; } pk;
        pk.ob[0] = __float2bfloat16(v.x); pk.ob[1] = __float2bfloat16(v.y);
        pk.ob[2] = __float2bfloat16(v.z); pk.ob[3] = __float2bfloat16(v.w);
        *(uint2*)(Wo_bf + idx4 * 4) = pk.u;
    }
}

// ---------------------------------------------------------------------------
// Kernel 2 (MFMA): encode.  p[(b,s,m),(h,f)] = atoms @ F^T as [32,64]@[64,256]
// per block, then sincos + softmax-weighted m-reduction.
// ---------------------------------------------------------------------------
__global__ __launch_bounds__(256) void encode(const float* __restrict__ qa_in,
                                              const float* __restrict__ ql,
                                              const float* __restrict__ ka_in,
                                              const float* __restrict__ kl,
                                              const bf16* __restrict__ Fqb,
                                              const bf16* __restrict__ Fkb,
                                              bf16* __restrict__ q_enc,
                                              bf16* __restrict__ k_enc) {
    int blk = blockIdx.x;
    int xbase = blk * 4;             // 4 (b,s) groups
    int b = xbase >> 10, s0 = xbase & 1023;
    __shared__ float wgtL[2][32];
    __shared__ __align__(16) bf16 zL[2 * 4 * 8 * 64];   // 8KB
    int t = threadIdx.x;
    int w = t >> 6, l = t & 63;
    int quad = l >> 4, r = l & 15;
    int tw = w & 1, nb = (w >> 1) * 8;

    if (t < 64) {
        int which = t >> 5, row = t & 31;
        int si = row >> 3, m = row & 7;
        const float* lwp = (which ? kl : ql) + (size_t)(xbase + si) * 8;
        float lw[8]; float mx = -1e30f;
        #pragma unroll
        for (int j = 0; j < 8; ++j) { lw[j] = lwp[j]; mx = fmaxf(mx, lw[j]); }
        float sm = 0.f;
        #pragma unroll
        for (int j = 0; j < 8; ++j) sm += __expf(lw[j] - mx);
        const float rs = 0.17677669529663687f;  // 1/sqrt(32)
        float osc = which ? rs : rs * 0.125f;
        wgtL[which][row] = __expf(lw[m] - mx) * (osc / sm);
    }
    __syncthreads();

    for (int which = 0; which < 2; ++which) {
        const float* at = which ? ka_in : qa_in;
        const bf16* Fb = which ? Fkb : Fqb;

        const float* arow = at + ((size_t)(blk * 32 + tw * 16 + r)) * 64 + quad * 8;
        float4 af0 = *(const float4*)(arow);
        float4 af1 = *(const float4*)(arow + 4);
        float4 af2 = *(const float4*)(arow + 32);
        float4 af3 = *(const float4*)(arow + 36);
        short8 a0 = pack8(af0, af1);
        short8 a1 = pack8(af2, af3);

        floatx4 acc[8];
        #pragma unroll
        for (int nt = 0; nt < 8; ++nt) {
            int n = (nb + nt) * 16 + r;
            short8 b0 = *(const short8*)(Fb + n * 64 + quad * 8);
            short8 b1 = *(const short8*)(Fb + n * 64 + quad * 8 + 32);
            floatx4 c = {0.f, 0.f, 0.f, 0.f};
            c = mfma16(a0, b0, c);
            c = mfma16(a1, b1, c);
            acc[nt] = c;
        }

        float wv[4];
        #pragma unroll
        for (int reg = 0; reg < 4; ++reg)
            wv[reg] = wgtL[which][tw * 16 + quad * 4 + reg];

        int si = tw * 2 + (quad >> 1);
        int iss = quad & 1;
        #pragma unroll
        for (int nt = 0; nt < 8; ++nt) {
            int n = (nb + nt) * 16 + r;
            int h = n >> 5, f = n & 31;
            float zc = 0.f, zs = 0.f;
            #pragma unroll
            for (int reg = 0; reg < 4; ++reg) {
                float sv, cv;
                __sincosf(acc[nt][reg], &sv, &cv);
                zc += wv[reg] * cv;
                zs += wv[reg] * sv;
            }
            zc += __shfl_xor(zc, 16);
            zs += __shfl_xor(zs, 16);
            float val = iss ? zs : zc;
            zL[((which * 4 + si) * 8 + h) * 64 + f + 32 * iss] = __float2bfloat16(val);
        }
    }
    __syncthreads();

    #pragma unroll
    for (int rep = 0; rep < 2; ++rep) {
        int idx = rep * 256 + t;
        int row = idx >> 3, c = idx & 7;
        int which = row >> 5, si = (row >> 3) & 3, h = row & 7;
        bf16* enc = which ? k_enc : q_enc;
        short8 v = *(const short8*)(zL + row * 64 + c * 8);
        *(short8*)(enc + ((size_t)((b * 8 + h) * 1024 + s0 + si)) * 64 + c * 8) = v;
    }
}

// ---------------------------------------------------------------------------
// Kernel 3: Vt[bh][n][k] (n = m*64+d, k = s), bf16, n-major for MFMA B-frags.
// ---------------------------------------------------------------------------
__global__ __launch_bounds__(256) void vproj(const float* __restrict__ va_in,
                                             const float* __restrict__ Wv,
                                             bf16* __restrict__ Vt) {
    int x = blockIdx.x;
    int b = x >> 7, s0 = (x & 127) * 8;
    __shared__ float atv[8][64][8];
    int t = threadIdx.x;
    const float* src = va_in + ((size_t)(b * 1024 + s0)) * 512;
    #pragma unroll
    for (int i = 0; i < 4; ++i) {
        int idx4 = t + 256 * i;
        float4 v4 = ((const float4*)src)[idx4];
        int flat = idx4 * 4;
        int si = flat >> 9, m = (flat >> 6) & 7, e = flat & 63;
        atv[m][e + 0][si] = v4.x;
        atv[m][e + 1][si] = v4.y;
        atv[m][e + 2][si] = v4.z;
        atv[m][e + 3][si] = v4.w;
    }
    __syncthreads();
    for (int rep = 0; rep < 2; ++rep) {
        int c = rep * 256 + t;
        int h = c >> 6, d = c & 63;
        float w[64];
        #pragma unroll
        for (int e4 = 0; e4 < 16; ++e4) {
            float4 wv = ((const float4*)(Wv + c * 64))[e4];
            w[e4 * 4 + 0] = wv.x; w[e4 * 4 + 1] = wv.y;
            w[e4 * 4 + 2] = wv.z; w[e4 * 4 + 3] = wv.w;
        }
        for (int m = 0; m < 8; ++m) {
            float acc[8] = {0, 0, 0, 0, 0, 0, 0, 0};
            for (int e = 0; e < 64; ++e) {
                float we = w[e];
                const float4 p0 = *(const float4*)&atv[m][e][0];
                const float4 p1 = *(const float4*)&atv[m][e][4];
                acc[0] += p0.x * we; acc[1] += p0.y * we;
                acc[2] += p0.z * we; acc[3] += p0.w * we;
                acc[4] += p1.x * we; acc[5] += p1.y * we;
                acc[6] += p1.z * we; acc[7] += p1.w * we;
            }
            union { bf16 ob[8]; uint4 u; } pk;
            #pragma unroll
            for (int si = 0; si < 8; ++si) pk.ob[si] = __float2bfloat16(acc[si]);
            *(uint4*)(Vt + ((size_t)((b * 8 + h) * 512 + m * 64 + d)) * 1024 + s0) = pk.u;
        }
    }
}

// ---------------------------------------------------------------------------
// Kernel 4: flash-style attention via MFMA.  1024 blocks (XCD-affine), 4 waves.
// 32 q-rows/block; k processed in 2 chunks of 512 with online softmax.
// Sc[32][520] bf16 = 33.3KB -> 4 blocks/CU.  Transposed QK^T (D[k][q]) so
// score C-regs pack into ds_write_b64.
// ---------------------------------------------------------------------------
__global__ __launch_bounds__(256) void attn_kern(const bf16* __restrict__ q_enc,
                                                 const bf16* __restrict__ k_enc,
                                                 const bf16* __restrict__ Vt,
                                                 bf16* __restrict__ tmp) {
    int n = blockIdx.x;
    int bh = (n & 7) + 8 * (n >> 8);
    int qb = (n >> 3) & 31;
    int b = bh >> 3, h = bh & 7;

    __shared__ __align__(16) bf16 Sc[32 * SC_STRIDE];   // 33.3 KB
    __shared__ float alphaL[32];
    __shared__ float invL[32];
    int t = threadIdx.x;
    int w = t >> 6, l = t & 63;
    int quad = l >> 4, r = l & 15;

    // Q B-fragments (n = q-row); q pre-scaled by 1/sqrt(D) in encode
    const bf16* qbase = q_enc + ((size_t)(bh * 1024 + qb * 32 + r)) * 64 + quad * 8;
    short8 q0 = *(const short8*)(qbase);
    short8 q1 = *(const short8*)(qbase + 32);
    short8 q2 = *(const short8*)(qbase + 16 * 64);
    short8 q3 = *(const short8*)(qbase + 16 * 64 + 32);

    floatx4 acc0[8], acc1[8];
    #pragma unroll
    for (int nt = 0; nt < 8; ++nt) {
        acc0[nt] = (floatx4){0.f, 0.f, 0.f, 0.f};
        acc1[nt] = (floatx4){0.f, 0.f, 0.f, 0.f};
    }

    // online-softmax state for rows w*8 + i (owned by wave w)
    float m_run[8], l_run[8];
    #pragma unroll
    for (int i = 0; i < 8; ++i) { m_run[i] = -1e30f; l_run[i] = 0.f; }

    const bf16* vbase = Vt + ((size_t)(bh * 512 + w * 128 + r)) * 1024 + quad * 8;

    for (int c = 0; c < 2; ++c) {
        // ---- Phase 1: scores (transposed: A=K-tile, B=Q-tiles -> D[k][q])
        // wave w: local k-tiles w*8 .. w*8+7 of this chunk
        const bf16* kb = k_enc + ((size_t)(bh * 1024 + c * 512 + r)) * 64 + quad * 8;
        short8 nk0 = *(const short8*)(kb + (size_t)(w * 8) * 16 * 64);
        short8 nk1 = *(const short8*)(kb + (size_t)(w * 8) * 16 * 64 + 32);
        for (int i = 0; i < 8; ++i) {
            short8 k0 = nk0, k1 = nk1;
            if (i < 7) {
                nk0 = *(const short8*)(kb + (size_t)((w * 8 + i + 1) * 16) * 64);
                nk1 = *(const short8*)(kb + (size_t)((w * 8 + i + 1) * 16) * 64 + 32);
            }
            floatx4 c0 = {0.f, 0.f, 0.f, 0.f}, c1 = {0.f, 0.f, 0.f, 0.f};
            c0 = mfma16(k0, q0, c0); c0 = mfma16(k1, q1, c0);
            c1 = mfma16(k0, q2, c1); c1 = mfma16(k1, q3, c1);
            int ktl = w * 8 + i;
            // c0[reg]: score(k = ktl*16 + quad*4 + reg, q-row = r)  -> b64 pack
            union { uint2 u; bf16 bb[4]; } p0, p1;
            #pragma unroll
            for (int reg = 0; reg < 4; ++reg) {
                p0.bb[reg] = __float2bfloat16(c0[reg]);
                p1.bb[reg] = __float2bfloat16(c1[reg]);
            }
            *(uint2*)(Sc + r * SC_STRIDE + ktl * 16 + quad * 4) = p0.u;
            *(uint2*)(Sc + (16 + r) * SC_STRIDE + ktl * 16 + quad * 4) = p1.u;
        }
        __syncthreads();

        // ---- Phase 2: online softmax partial (wave w: rows w*8..w*8+7)
        #pragma unroll
        for (int i = 0; i < 8; ++i) {
            int row = w * 8 + i;
            bf16* rowp = Sc + row * SC_STRIDE;
            union { short8 s; unsigned short u[8]; } v;
            v.s = *(const short8*)(rowp + l * 8);
            float f[8];
            #pragma unroll
            for (int j = 0; j < 8; ++j) f[j] = us2f(v.u[j]);
            float mx = f[0];
            #pragma unroll
            for (int j = 1; j < 8; ++j) mx = fmaxf(mx, f[j]);
            #pragma unroll
            for (int off = 32; off; off >>= 1) mx = fmaxf(mx, __shfl_xor(mx, off));
            float mnew = fmaxf(m_run[i], mx);
            float al = __expf(m_run[i] - mnew);
            float sm = 0.f;
            #pragma unroll
            for (int j = 0; j < 8; ++j) { f[j] = __expf(f[j] - mnew); sm += f[j]; }
            #pragma unroll
            for (int off = 32; off; off >>= 1) sm += __shfl_xor(sm, off);
            l_run[i] = l_run[i] * al + sm;
            m_run[i] = mnew;
            #pragma unroll
            for (int j = 0; j < 8; ++j)
                v.u[j] = __bfloat16_as_ushort(__float2bfloat16(f[j]));
            *(short8*)(rowp + l * 8) = v.s;
            if (l == 0) {
                alphaL[row] = al;
                if (c == 1) invL[row] = 1.f / l_run[i];
            }
        }
        __syncthreads();

        // ---- Phase 3: rescale acc by alpha, then P@V for this chunk
        float4 a0v = *(const float4*)&alphaL[quad * 4];
        float4 a1v = *(const float4*)&alphaL[16 + quad * 4];
        floatx4 av0 = {a0v.x, a0v.y, a0v.z, a0v.w};
        floatx4 av1 = {a1v.x, a1v.y, a1v.z, a1v.w};
        #pragma unroll
        for (int nt = 0; nt < 8; ++nt) { acc0[nt] *= av0; acc1[nt] *= av1; }

        const bf16* vc = vbase + c * 512;
        short8 cur[8], nxt[8];
        #pragma unroll
        for (int nt = 0; nt < 8; ++nt) nxt[nt] = *(const short8*)(vc + nt * 16384);
        for (int ks = 0; ks < 16; ++ks) {
            #pragma unroll
            for (int nt = 0; nt < 8; ++nt) cur[nt] = nxt[nt];
            if (ks < 15) {
                #pragma unroll
                for (int nt = 0; nt < 8; ++nt)
                    nxt[nt] = *(const short8*)(vc + nt * 16384 + (ks + 1) * 32);
            }
            short8 pa0 = *(const short8*)(Sc + r * SC_STRIDE + ks * 32 + quad * 8);
            short8 pa1 = *(const short8*)(Sc + (16 + r) * SC_STRIDE + ks * 32 + quad * 8);
            #pragma unroll
            for (int nt = 0; nt < 8; ++nt) {
                acc0[nt] = mfma16(pa0, cur[nt], acc0[nt]);
                acc1[nt] = mfma16(pa1, cur[nt], acc1[nt]);
            }
        }
        __syncthreads();   // Sc reads done before next chunk overwrites / epilogue
    }

    // ---- Epilogue: normalize by 1/l_final, stage in Sc, coalesced store
    float4 i0v = *(const float4*)&invL[quad * 4];
    float4 i1v = *(const float4*)&invL[16 + quad * 4];
    float iva0[4] = {i0v.x, i0v.y, i0v.z, i0v.w};
    float iva1[4] = {i1v.x, i1v.y, i1v.z, i1v.w};
    bf16* Ob = Sc;
    #pragma unroll
    for (int nt = 0; nt < 8; ++nt)
        #pragma unroll
        for (int reg = 0; reg < 4; ++reg) {
            int col = w * 128 + nt * 16 + r;
            Ob[(quad * 4 + reg) * SC_STRIDE + col] = __float2bfloat16(acc0[nt][reg] * iva0[reg]);
            Ob[(quad * 4 + reg + 16) * SC_STRIDE + col] = __float2bfloat16(acc1[nt][reg] * iva1[reg]);
        }
    __syncthreads();

    // coalesced store: 32 rows x 512 cols bf16 -> tmp[b][q][m][h][d]
    #pragma unroll
    for (int i = 0; i < 8; ++i) {
        int cix = i * 256 + t;
        int row = cix >> 6, j = cix & 63;
        int m = j >> 3, d0 = (j & 7) * 8;
        short8 v = *(const short8*)(Ob + row * SC_STRIDE + j * 8);
        *(short8*)(tmp + ((((size_t)(b * 1024 + qb * 32 + row) * 8 + m) * 8 + h) * 64 + d0)) = v;
    }
}

// ---------------------------------------------------------------------------
// Kernel 5 (MFMA): out_atoms[row, o] = tmp[row, :512] @ Wo_bf[o, :512]
// ---------------------------------------------------------------------------
__global__ __launch_bounds__(256) void finalize(const bf16* __restrict__ tmp,
                                                const bf16* __restrict__ Wo_bf,
                                                const float* __restrict__ Ww,
                                                const float* __restrict__ ql,
                                                float* __restrict__ out) {
    __shared__ __align__(16) float Os[64][OS_STRIDE];   // 17.4 KB
    __shared__ float fs[8][64];
    int t = threadIdx.x;
    int w = t >> 6, l = t & 63;
    int quad = l >> 4, r = l & 15;
    size_t rowbase = (size_t)blockIdx.x * 64;

    floatx4 acc[4];
    #pragma unroll
    for (int nt = 0; nt < 4; ++nt) acc[nt] = (floatx4){0.f, 0.f, 0.f, 0.f};

    const bf16* arow = tmp + (rowbase + w * 16 + r) * 512 + quad * 8;
    const bf16* brow = Wo_bf + r * 512 + quad * 8;

    for (int ks = 0; ks < 16; ++ks) {
        short8 a = *(const short8*)(arow + ks * 32);
        #pragma unroll
        for (int nt = 0; nt < 4; ++nt) {
            short8 bb = *(const short8*)(brow + nt * 16 * 512 + ks * 32);
            acc[nt] = mfma16(a, bb, acc[nt]);
        }
    }
    #pragma unroll
    for (int nt = 0; nt < 4; ++nt)
        #pragma unroll
        for (int reg = 0; reg < 4; ++reg)
            Os[w * 16 + quad * 4 + reg][nt * 16 + r] = acc[nt][reg];
    __syncthreads();

    #pragma unroll
    for (int i = 0; i < 4; ++i) {
        int ch = i * 256 + t;
        int rr = ch >> 4, c4 = (ch & 15) * 4;
        float4 v = *(const float4*)&Os[rr][c4];
        *(float4*)(out + (rowbase + rr) * 64 + c4) = v;
    }

    {
        int g = t >> 5, oo = (t & 31) * 2;
        float f0 = 0.f, f1 = 0.f;
        #pragma unroll
        for (int m = 0; m < 8; ++m) {
            f0 += Os[g * 8 + m][oo];
            f1 += Os[g * 8 + m][oo + 1];
        }
        fs[g][oo] = f0 * 0.125f;
        fs[g][oo + 1] = f1 * 0.125f;
    }
    __syncthreads();

    if (t < 64) {
        int g = t >> 3, mm = t & 7;
        size_t x = (size_t)blockIdx.x * 8 + g;
        float nl = ql[x * 8 + mm];
        #pragma unroll
        for (int o = 0; o < 64; ++o) nl += fs[g][o] * Ww[mm * 64 + o];
        out[(size_t)CB * CS * CM * CD + x * 8 + mm] = nl;
    }
}

// ---------------------------------------------------------------------------
extern "C" void kernel_launch(void* const* d_in, const int* in_sizes, int n_in,
                              void* d_out, int out_size, void* d_ws, size_t ws_size,
                              hipStream_t stream) {
    const float* q_atoms = (const float*)d_in[0];
    const float* q_logw  = (const float*)d_in[1];
    const float* k_atoms = (const float*)d_in[2];
    const float* k_logw  = (const float*)d_in[3];
    const float* v_atoms = (const float*)d_in[4];
    // d_in[5] = v_logw (unused by the reference)
    const float* Wq = (const float*)d_in[6];
    const float* Wk = (const float*)d_in[7];
    const float* Wv = (const float*)d_in[8];
    const float* Wo = (const float*)d_in[9];
    const float* Ww = (const float*)d_in[10];
    const float* freqs = (const float*)d_in[11];

    // ws layout (all bf16): Fqb[16384] | Fkb[16384] | q_enc[2097152]
    //   | k_enc[2097152] | Vt[16777216] | tmp[16777216] | Wo_bf[32768]
    bf16* Fqb = (bf16*)d_ws;
    bf16* Fkb = Fqb + 16384;
    bf16* q_enc = Fkb + 16384;
    bf16* k_enc = q_enc + 2097152;
    bf16* Vt = k_enc + 2097152;
    bf16* tmp = Vt + 16777216;
    bf16* Wo_bf = tmp + 16777216;
    float* out = (float*)d_out;

    prep_F<<<16, 256, 0, stream>>>(Wq, Wk, freqs, Wo, Fqb, Fkb, Wo_bf);
    encode<<<1024, 256, 0, stream>>>(q_atoms, q_logw, k_atoms, k_logw,
                                     Fqb, Fkb, q_enc, k_enc);
    vproj<<<CB * CS / 8, 256, 0, stream>>>(v_atoms, Wv, Vt);
    attn_kern<<<1024, 256, 0, stream>>>(q_enc, k_enc, Vt, tmp);
    finalize<<<CB * CS / 8, 256, 0, stream>>>(tmp, Wo_bf, Ww, q_logw, out);
}

// Round 8
// 378.966 us; speedup vs baseline: 1.1878x; 1.1878x over previous
//
#include <hip/hip_runtime.h>
#include <hip/hip_bf16.h>

typedef __hip_bfloat16 bf16;
typedef __attribute__((ext_vector_type(8))) short short8;
typedef __attribute__((ext_vector_type(4))) float floatx4;

// Problem constants: B=4, S=1024, M=8, D=64, H=8, NF=32, HD=512
#define CB 4
#define CS 1024
#define CM 8
#define CD 64
#define CH 8
#define CNF 32
#define CHD 512

#define OB_STRIDE 520    // attn epilogue staging stride (bf16): 16B-aligned rows
#define OS_STRIDE 68     // finalize staging stride (fp32)

__device__ __forceinline__ float b2f(bf16 x) { return __bfloat162float(x); }
__device__ __forceinline__ float us2f(unsigned short u) {
    union { unsigned int i; float f; } v; v.i = ((unsigned int)u) << 16; return v.f;
}
__device__ __forceinline__ floatx4 mfma16(short8 a, short8 b, floatx4 c) {
    return __builtin_amdgcn_mfma_f32_16x16x32_bf16(a, b, c, 0, 0, 0);
}
__device__ __forceinline__ short8 pack8(float4 x, float4 y) {
    union { short8 s; bf16 b[8]; } u;
    u.b[0] = __float2bfloat16(x.x); u.b[1] = __float2bfloat16(x.y);
    u.b[2] = __float2bfloat16(x.z); u.b[3] = __float2bfloat16(x.w);
    u.b[4] = __float2bfloat16(y.x); u.b[5] = __float2bfloat16(y.y);
    u.b[6] = __float2bfloat16(y.z); u.b[7] = __float2bfloat16(y.w);
    return u.s;
}

// ---------------------------------------------------------------------------
// Kernel 1: Fb[which][n=h*32+f][e] (bf16, n-major MFMA B-layout)
//   = sum_d W[h*64+d][e] * freqs[h][d][f];  + convert Wo -> bf16.
// ---------------------------------------------------------------------------
__global__ __launch_bounds__(256) void prep_F(const float* __restrict__ Wq,
                                              const float* __restrict__ Wk,
                                              const float* __restrict__ freqs,
                                              const float* __restrict__ Wo,
                                              bf16* __restrict__ Fqb,
                                              bf16* __restrict__ Fkb,
                                              bf16* __restrict__ Wo_bf) {
    int h = blockIdx.x & 7;
    int which = blockIdx.x >> 3;
    const float* W = which ? Wk : Wq;
    bf16* Fb = which ? Fkb : Fqb;
    int t = threadIdx.x;
    int f = t & 31, e0 = t >> 5;
    for (int ei = 0; ei < 8; ++ei) {
        int e = ei * 8 + e0;
        float acc = 0.f;
        for (int d = 0; d < 64; ++d)
            acc += W[(h * 64 + d) * 64 + e] * freqs[(h * 64 + d) * 32 + f];
        Fb[(h * 32 + f) * 64 + e] = __float2bfloat16(acc);
    }
    int gid = blockIdx.x * 256 + t;
    #pragma unroll
    for (int i = 0; i < 2; ++i) {
        int idx4 = gid * 2 + i;
        float4 v = ((const float4*)Wo)[idx4];
        union { bf16 ob[4]; uint2 u; } pk;
        pk.ob[0] = __float2bfloat16(v.x); pk.ob[1] = __float2bfloat16(v.y);
        pk.ob[2] = __float2bfloat16(v.z); pk.ob[3] = __float2bfloat16(v.w);
        *(uint2*)(Wo_bf + idx4 * 4) = pk.u;
    }
}

// ---------------------------------------------------------------------------
// Kernel 2 (MFMA): encode.  p[(b,s,m),(h,f)] = atoms @ F^T as [32,64]@[64,256]
// per block, then sincos + softmax-weighted m-reduction.
// ---------------------------------------------------------------------------
__global__ __launch_bounds__(256) void encode(const float* __restrict__ qa_in,
                                              const float* __restrict__ ql,
                                              const float* __restrict__ ka_in,
                                              const float* __restrict__ kl,
                                              const bf16* __restrict__ Fqb,
                                              const bf16* __restrict__ Fkb,
                                              bf16* __restrict__ q_enc,
                                              bf16* __restrict__ k_enc) {
    int blk = blockIdx.x;
    int xbase = blk * 4;             // 4 (b,s) groups
    int b = xbase >> 10, s0 = xbase & 1023;
    __shared__ float wgtL[2][32];
    __shared__ __align__(16) bf16 zL[2 * 4 * 8 * 64];   // 8KB
    int t = threadIdx.x;
    int w = t >> 6, l = t & 63;
    int quad = l >> 4, r = l & 15;
    int tw = w & 1, nb = (w >> 1) * 8;

    if (t < 64) {
        int which = t >> 5, row = t & 31;
        int si = row >> 3, m = row & 7;
        const float* lwp = (which ? kl : ql) + (size_t)(xbase + si) * 8;
        float lw[8]; float mx = -1e30f;
        #pragma unroll
        for (int j = 0; j < 8; ++j) { lw[j] = lwp[j]; mx = fmaxf(mx, lw[j]); }
        float sm = 0.f;
        #pragma unroll
        for (int j = 0; j < 8; ++j) sm += __expf(lw[j] - mx);
        const float rs = 0.17677669529663687f;  // 1/sqrt(32)
        float osc = which ? rs : rs * 0.125f;
        wgtL[which][row] = __expf(lw[m] - mx) * (osc / sm);
    }
    __syncthreads();

    for (int which = 0; which < 2; ++which) {
        const float* at = which ? ka_in : qa_in;
        const bf16* Fb = which ? Fkb : Fqb;

        const float* arow = at + ((size_t)(blk * 32 + tw * 16 + r)) * 64 + quad * 8;
        float4 af0 = *(const float4*)(arow);
        float4 af1 = *(const float4*)(arow + 4);
        float4 af2 = *(const float4*)(arow + 32);
        float4 af3 = *(const float4*)(arow + 36);
        short8 a0 = pack8(af0, af1);
        short8 a1 = pack8(af2, af3);

        floatx4 acc[8];
        #pragma unroll
        for (int nt = 0; nt < 8; ++nt) {
            int n = (nb + nt) * 16 + r;
            short8 b0 = *(const short8*)(Fb + n * 64 + quad * 8);
            short8 b1 = *(const short8*)(Fb + n * 64 + quad * 8 + 32);
            floatx4 c = {0.f, 0.f, 0.f, 0.f};
            c = mfma16(a0, b0, c);
            c = mfma16(a1, b1, c);
            acc[nt] = c;
        }

        float wv[4];
        #pragma unroll
        for (int reg = 0; reg < 4; ++reg)
            wv[reg] = wgtL[which][tw * 16 + quad * 4 + reg];

        int si = tw * 2 + (quad >> 1);
        int iss = quad & 1;
        #pragma unroll
        for (int nt = 0; nt < 8; ++nt) {
            int n = (nb + nt) * 16 + r;
            int h = n >> 5, f = n & 31;
            float zc = 0.f, zs = 0.f;
            #pragma unroll
            for (int reg = 0; reg < 4; ++reg) {
                float sv, cv;
                __sincosf(acc[nt][reg], &sv, &cv);
                zc += wv[reg] * cv;
                zs += wv[reg] * sv;
            }
            zc += __shfl_xor(zc, 16);
            zs += __shfl_xor(zs, 16);
            float val = iss ? zs : zc;
            zL[((which * 4 + si) * 8 + h) * 64 + f + 32 * iss] = __float2bfloat16(val);
        }
    }
    __syncthreads();

    #pragma unroll
    for (int rep = 0; rep < 2; ++rep) {
        int idx = rep * 256 + t;
        int row = idx >> 3, c = idx & 7;
        int which = row >> 5, si = (row >> 3) & 3, h = row & 7;
        bf16* enc = which ? k_enc : q_enc;
        short8 v = *(const short8*)(zL + row * 64 + c * 8);
        *(short8*)(enc + ((size_t)((b * 8 + h) * 1024 + s0 + si)) * 64 + c * 8) = v;
    }
}

// ---------------------------------------------------------------------------
// Kernel 3: Vt[bh][n][k] (n = m*64+d, k = s), bf16, n-major for MFMA B-frags.
// ---------------------------------------------------------------------------
__global__ __launch_bounds__(256) void vproj(const float* __restrict__ va_in,
                                             const float* __restrict__ Wv,
                                             bf16* __restrict__ Vt) {
    int x = blockIdx.x;
    int b = x >> 7, s0 = (x & 127) * 8;
    __shared__ float atv[8][64][8];
    int t = threadIdx.x;
    const float* src = va_in + ((size_t)(b * 1024 + s0)) * 512;
    #pragma unroll
    for (int i = 0; i < 4; ++i) {
        int idx4 = t + 256 * i;
        float4 v4 = ((const float4*)src)[idx4];
        int flat = idx4 * 4;
        int si = flat >> 9, m = (flat >> 6) & 7, e = flat & 63;
        atv[m][e + 0][si] = v4.x;
        atv[m][e + 1][si] = v4.y;
        atv[m][e + 2][si] = v4.z;
        atv[m][e + 3][si] = v4.w;
    }
    __syncthreads();
    for (int rep = 0; rep < 2; ++rep) {
        int c = rep * 256 + t;
        int h = c >> 6, d = c & 63;
        float w[64];
        #pragma unroll
        for (int e4 = 0; e4 < 16; ++e4) {
            float4 wv = ((const float4*)(Wv + c * 64))[e4];
            w[e4 * 4 + 0] = wv.x; w[e4 * 4 + 1] = wv.y;
            w[e4 * 4 + 2] = wv.z; w[e4 * 4 + 3] = wv.w;
        }
        for (int m = 0; m < 8; ++m) {
            float acc[8] = {0, 0, 0, 0, 0, 0, 0, 0};
            for (int e = 0; e < 64; ++e) {
                float we = w[e];
                const float4 p0 = *(const float4*)&atv[m][e][0];
                const float4 p1 = *(const float4*)&atv[m][e][4];
                acc[0] += p0.x * we; acc[1] += p0.y * we;
                acc[2] += p0.z * we; acc[3] += p0.w * we;
                acc[4] += p1.x * we; acc[5] += p1.y * we;
                acc[6] += p1.z * we; acc[7] += p1.w * we;
            }
            union { bf16 ob[8]; uint4 u; } pk;
            #pragma unroll
            for (int si = 0; si < 8; ++si) pk.ob[si] = __float2bfloat16(acc[si]);
            *(uint4*)(Vt + ((size_t)((b * 8 + h) * 512 + m * 64 + d)) * 1024 + s0) = pk.u;
        }
    }
}

// ---------------------------------------------------------------------------
// Kernel 4: attention via MFMA.  1024 blocks (XCD-affine bh mapping), 4 waves.
// 32 q-rows/block; Sc[32][1024] bf16 = 64KB LDS, XOR-swizzled 16B chunks.
// Transposed QK^T (D[k][q]) -> packed b64 swizzled score writes.
// Distance-2 prefetch on K (P1) and V (P3) load streams.
// ---------------------------------------------------------------------------
__global__ __launch_bounds__(256, 2) void attn_kern(const bf16* __restrict__ q_enc,
                                                    const bf16* __restrict__ k_enc,
                                                    const bf16* __restrict__ Vt,
                                                    bf16* __restrict__ tmp) {
    int n = blockIdx.x;
    int bh = (n & 7) + 8 * (n >> 8);
    int qb = (n >> 3) & 31;
    int b = bh >> 3, h = bh & 7;

    __shared__ __align__(16) bf16 Sc[32 * 1024];   // 64KB
    int t = threadIdx.x;
    int w = t >> 6, l = t & 63;
    int quad = l >> 4, r = l & 15;
    int k7 = r & 7;

    // ---- Phase 1: QK^T transposed (A=K-tile, B=Q-tiles -> D[k][q]).
    // q pre-scaled by 1/sqrt(D) in encode.
    const bf16* qbase = q_enc + ((size_t)(bh * 1024 + qb * 32 + r)) * 64 + quad * 8;
    short8 q0 = *(const short8*)(qbase);
    short8 q1 = *(const short8*)(qbase + 32);
    short8 q2 = *(const short8*)(qbase + 16 * 64);
    short8 q3 = *(const short8*)(qbase + 16 * 64 + 32);

    // wave w handles k-tiles w*16 .. w*16+15; distance-2 prefetch
    const bf16* kb = k_enc + ((size_t)(bh * 1024 + r)) * 64 + quad * 8;
    short8 kA0 = *(const short8*)(kb + (size_t)(w * 16) * 16 * 64);
    short8 kA1 = *(const short8*)(kb + (size_t)(w * 16) * 16 * 64 + 32);
    short8 kB0 = *(const short8*)(kb + (size_t)(w * 16 + 1) * 16 * 64);
    short8 kB1 = *(const short8*)(kb + (size_t)(w * 16 + 1) * 16 * 64 + 32);

    #pragma unroll
    for (int i = 0; i < 16; ++i) {
        short8 k0 = kA0, k1 = kA1;
        kA0 = kB0; kA1 = kB1;
        if (i < 14) {
            kB0 = *(const short8*)(kb + (size_t)((w * 16 + i + 2) * 16) * 64);
            kB1 = *(const short8*)(kb + (size_t)((w * 16 + i + 2) * 16) * 64 + 32);
        }
        floatx4 c0 = {0.f, 0.f, 0.f, 0.f}, c1 = {0.f, 0.f, 0.f, 0.f};
        c0 = mfma16(k0, q0, c0); c0 = mfma16(k1, q1, c0);
        c1 = mfma16(k0, q2, c1); c1 = mfma16(k1, q3, c1);
        // c0[reg] = score(k = ktl*16 + quad*4 + reg, q-row r); c1 -> q-row r+16
        int ktl = w * 16 + i;
        int chunk = ktl * 2 + (quad >> 1);          // 8-short chunk index
        int sw = ((chunk ^ k7) << 3) + (quad & 1) * 4;
        union { uint2 u; bf16 bb[4]; } p0, p1;
        #pragma unroll
        for (int reg = 0; reg < 4; ++reg) {
            p0.bb[reg] = __float2bfloat16(c0[reg]);
            p1.bb[reg] = __float2bfloat16(c1[reg]);
        }
        *(uint2*)(Sc + r * 1024 + sw) = p0.u;
        *(uint2*)(Sc + (r + 16) * 1024 + sw) = p1.u;
    }
    __syncthreads();

    // ---- Phase 2: softmax, normalized in place (wave w: rows w*8..w*8+7)
    for (int i = 0; i < 8; ++i) {
        int row = w * 8 + i;
        int key = row & 7;
        bf16* rowp = Sc + row * 1024;
        int p0 = ((2 * l) ^ key) << 3;
        int p1 = ((2 * l + 1) ^ key) << 3;
        union { short8 s; unsigned short u[8]; } v0, v1;
        v0.s = *(const short8*)(rowp + p0);
        v1.s = *(const short8*)(rowp + p1);
        float f[16];
        #pragma unroll
        for (int j = 0; j < 8; ++j) { f[j] = us2f(v0.u[j]); f[8 + j] = us2f(v1.u[j]); }
        float mx = -1e30f;
        #pragma unroll
        for (int j = 0; j < 16; ++j) mx = fmaxf(mx, f[j]);
        #pragma unroll
        for (int off = 32; off; off >>= 1) mx = fmaxf(mx, __shfl_xor(mx, off));
        float sm = 0.f;
        #pragma unroll
        for (int j = 0; j < 16; ++j) { f[j] = __expf(f[j] - mx); sm += f[j]; }
        #pragma unroll
        for (int off = 32; off; off >>= 1) sm += __shfl_xor(sm, off);
        float inv = 1.f / sm;
        #pragma unroll
        for (int j = 0; j < 8; ++j) {
            v0.u[j] = (unsigned short)(__bfloat16_as_ushort(__float2bfloat16(f[j] * inv)));
            v1.u[j] = (unsigned short)(__bfloat16_as_ushort(__float2bfloat16(f[8 + j] * inv)));
        }
        *(short8*)(rowp + p0) = v0.s;
        *(short8*)(rowp + p1) = v1.s;
    }
    __syncthreads();

    // ---- Phase 3: P@V.  wave w: n-cols [w*128, w*128+128), both 16-row tiles.
    // Distance-2 prefetch: 3 live batches of 8 V-fragments.
    floatx4 acc0[8], acc1[8];
    #pragma unroll
    for (int nt = 0; nt < 8; ++nt) {
        acc0[nt] = (floatx4){0.f, 0.f, 0.f, 0.f};
        acc1[nt] = (floatx4){0.f, 0.f, 0.f, 0.f};
    }
    const bf16* vbase = Vt + ((size_t)(bh * 512 + w * 128 + r)) * 1024 + quad * 8;
    short8 vA[8], vB[8], vC[8];
    #pragma unroll
    for (int nt = 0; nt < 8; ++nt) vA[nt] = *(const short8*)(vbase + nt * 16384);
    #pragma unroll
    for (int nt = 0; nt < 8; ++nt) vB[nt] = *(const short8*)(vbase + nt * 16384 + 32);

    #pragma unroll
    for (int ks = 0; ks < 32; ++ks) {
        if (ks < 30) {
            #pragma unroll
            for (int nt = 0; nt < 8; ++nt)
                vC[nt] = *(const short8*)(vbase + nt * 16384 + (ks + 2) * 32);
        }
        int pc = (((ks * 4 + quad) ^ k7) << 3);
        short8 pa0 = *(const short8*)(Sc + r * 1024 + pc);
        short8 pa1 = *(const short8*)(Sc + (16 + r) * 1024 + pc);
        #pragma unroll
        for (int nt = 0; nt < 8; ++nt) {
            acc0[nt] = mfma16(pa0, vA[nt], acc0[nt]);
            acc1[nt] = mfma16(pa1, vA[nt], acc1[nt]);
        }
        #pragma unroll
        for (int nt = 0; nt < 8; ++nt) { vA[nt] = vB[nt]; vB[nt] = vC[nt]; }
    }
    __syncthreads();   // all Sc reads done; reuse for output staging

    bf16* Ob = Sc;
    #pragma unroll
    for (int nt = 0; nt < 8; ++nt)
        #pragma unroll
        for (int reg = 0; reg < 4; ++reg) {
            int col = w * 128 + nt * 16 + r;
            Ob[(quad * 4 + reg) * OB_STRIDE + col] = __float2bfloat16(acc0[nt][reg]);
            Ob[(quad * 4 + reg + 16) * OB_STRIDE + col] = __float2bfloat16(acc1[nt][reg]);
        }
    __syncthreads();

    // coalesced store: 32 rows x 512 cols bf16 -> tmp[b][q][m][h][d]
    #pragma unroll
    for (int i = 0; i < 8; ++i) {
        int c = i * 256 + t;
        int row = c >> 6, j = c & 63;
        int m = j >> 3, d0 = (j & 7) * 8;
        short8 v = *(const short8*)(Ob + row * OB_STRIDE + j * 8);
        *(short8*)(tmp + ((((size_t)(b * 1024 + qb * 32 + row) * 8 + m) * 8 + h) * 64 + d0)) = v;
    }
}

// ---------------------------------------------------------------------------
// Kernel 5 (MFMA): out_atoms[row, o] = tmp[row, :512] @ Wo_bf[o, :512]
// ---------------------------------------------------------------------------
__global__ __launch_bounds__(256) void finalize(const bf16* __restrict__ tmp,
                                                const bf16* __restrict__ Wo_bf,
                                                const float* __restrict__ Ww,
                                                const float* __restrict__ ql,
                                                float* __restrict__ out) {
    __shared__ __align__(16) float Os[64][OS_STRIDE];   // 17.4 KB
    __shared__ float fs[8][64];
    int t = threadIdx.x;
    int w = t >> 6, l = t & 63;
    int quad = l >> 4, r = l & 15;
    size_t rowbase = (size_t)blockIdx.x * 64;

    floatx4 acc[4];
    #pragma unroll
    for (int nt = 0; nt < 4; ++nt) acc[nt] = (floatx4){0.f, 0.f, 0.f, 0.f};

    const bf16* arow = tmp + (rowbase + w * 16 + r) * 512 + quad * 8;
    const bf16* brow = Wo_bf + r * 512 + quad * 8;

    for (int ks = 0; ks < 16; ++ks) {
        short8 a = *(const short8*)(arow + ks * 32);
        #pragma unroll
        for (int nt = 0; nt < 4; ++nt) {
            short8 bb = *(const short8*)(brow + nt * 16 * 512 + ks * 32);
            acc[nt] = mfma16(a, bb, acc[nt]);
        }
    }
    #pragma unroll
    for (int nt = 0; nt < 4; ++nt)
        #pragma unroll
        for (int reg = 0; reg < 4; ++reg)
            Os[w * 16 + quad * 4 + reg][nt * 16 + r] = acc[nt][reg];
    __syncthreads();

    #pragma unroll
    for (int i = 0; i < 4; ++i) {
        int ch = i * 256 + t;
        int rr = ch >> 4, c4 = (ch & 15) * 4;
        float4 v = *(const float4*)&Os[rr][c4];
        *(float4*)(out + (rowbase + rr) * 64 + c4) = v;
    }

    {
        int g = t >> 5, oo = (t & 31) * 2;
        float f0 = 0.f, f1 = 0.f;
        #pragma unroll
        for (int m = 0; m < 8; ++m) {
            f0 += Os[g * 8 + m][oo];
            f1 += Os[g * 8 + m][oo + 1];
        }
        fs[g][oo] = f0 * 0.125f;
        fs[g][oo + 1] = f1 * 0.125f;
    }
    __syncthreads();

    if (t < 64) {
        int g = t >> 3, mm = t & 7;
        size_t x = (size_t)blockIdx.x * 8 + g;
        float nl = ql[x * 8 + mm];
        #pragma unroll
        for (int o = 0; o < 64; ++o) nl += fs[g][o] * Ww[mm * 64 + o];
        out[(size_t)CB * CS * CM * CD + x * 8 + mm] = nl;
    }
}

// ---------------------------------------------------------------------------
extern "C" void kernel_launch(void* const* d_in, const int* in_sizes, int n_in,
                              void* d_out, int out_size, void* d_ws, size_t ws_size,
                              hipStream_t stream) {
    const float* q_atoms = (const float*)d_in[0];
    const float* q_logw  = (const float*)d_in[1];
    const float* k_atoms = (const float*)d_in[2];
    const float* k_logw  = (const float*)d_in[3];
    const float* v_atoms = (const float*)d_in[4];
    // d_in[5] = v_logw (unused by the reference)
    const float* Wq = (const float*)d_in[6];
    const float* Wk = (const float*)d_in[7];
    const float* Wv = (const float*)d_in[8];
    const float* Wo = (const float*)d_in[9];
    const float* Ww = (const float*)d_in[10];
    const float* freqs = (const float*)d_in[11];

    // ws layout (all bf16): Fqb[16384] | Fkb[16384] | q_enc[2097152]
    //   | k_enc[2097152] | Vt[16777216] | tmp[16777216] | Wo_bf[32768]
    bf16* Fqb = (bf16*)d_ws;
    bf16* Fkb = Fqb + 16384;
    bf16* q_enc = Fkb + 16384;
    bf16* k_enc = q_enc + 2097152;
    bf16* Vt = k_enc + 2097152;
    bf16* tmp = Vt + 16777216;
    bf16* Wo_bf = tmp + 16777216;
    float* out = (float*)d_out;

    prep_F<<<16, 256, 0, stream>>>(Wq, Wk, freqs, Wo, Fqb, Fkb, Wo_bf);
    encode<<<1024, 256, 0, stream>>>(q_atoms, q_logw, k_atoms, k_logw,
                                     Fqb, Fkb, q_enc, k_enc);
    vproj<<<CB * CS / 8, 256, 0, stream>>>(v_atoms, Wv, Vt);
    attn_kern<<<1024, 256, 0, stream>>>(q_enc, k_enc, Vt, tmp);
    finalize<<<CB * CS / 8, 256, 0, stream>>>(tmp, Wo_bf, Ww, q_logw, out);
}

// Round 9
// 287.622 us; speedup vs baseline: 1.5651x; 1.3176x over previous
//
#include <hip/hip_runtime.h>
#include <hip/hip_bf16.h>

typedef __hip_bfloat16 bf16;
typedef __attribute__((ext_vector_type(8))) short short8;
typedef __attribute__((ext_vector_type(4))) float floatx4;

// Problem constants: B=4, S=1024, M=8, D=64, H=8, NF=32, HD=512
#define CB 4
#define CS 1024
#define CM 8
#define CD 64
#define CH 8
#define CNF 32
#define CHD 512

#define OB_STRIDE 520    // attn epilogue staging stride (bf16): 16B-aligned rows
#define OS_STRIDE 68     // finalize staging stride (fp32)
#define AT_STRIDE 72     // vproj atoms LDS row stride (shorts): 36 words -> bank spread
#define VO_STRIDE 40     // vproj output staging stride (shorts)

__device__ __forceinline__ float b2f(bf16 x) { return __bfloat162float(x); }
__device__ __forceinline__ float us2f(unsigned short u) {
    union { unsigned int i; float f; } v; v.i = ((unsigned int)u) << 16; return v.f;
}
__device__ __forceinline__ floatx4 mfma16(short8 a, short8 b, floatx4 c) {
    return __builtin_amdgcn_mfma_f32_16x16x32_bf16(a, b, c, 0, 0, 0);
}
__device__ __forceinline__ short8 pack8(float4 x, float4 y) {
    union { short8 s; bf16 b[8]; } u;
    u.b[0] = __float2bfloat16(x.x); u.b[1] = __float2bfloat16(x.y);
    u.b[2] = __float2bfloat16(x.z); u.b[3] = __float2bfloat16(x.w);
    u.b[4] = __float2bfloat16(y.x); u.b[5] = __float2bfloat16(y.y);
    u.b[6] = __float2bfloat16(y.z); u.b[7] = __float2bfloat16(y.w);
    return u.s;
}

// ---------------------------------------------------------------------------
// Kernel 1 (prep): 160 blocks.
//   blocks 0..127: Fb[which][n=h*32+f][e] = sum_d W[h*64+d][e]*freqs[h][d][f]
//                  (which = b>>6, h = (b>>3)&7, e-chunk = b&7)
//   blocks 128..143: Wo fp32 -> bf16
//   blocks 144..159: Wv fp32 -> bf16
// ---------------------------------------------------------------------------
__global__ __launch_bounds__(256) void prep(const float* __restrict__ Wq,
                                            const float* __restrict__ Wk,
                                            const float* __restrict__ freqs,
                                            const float* __restrict__ Wo,
                                            const float* __restrict__ Wv,
                                            bf16* __restrict__ Fqb,
                                            bf16* __restrict__ Fkb,
                                            bf16* __restrict__ Wo_bf,
                                            bf16* __restrict__ Wv_bf) {
    int bx = blockIdx.x, t = threadIdx.x;
    if (bx < 128) {
        int which = bx >> 6, h = (bx >> 3) & 7, ec = bx & 7;
        const float* W = which ? Wk : Wq;
        bf16* Fb = which ? Fkb : Fqb;
        int f = t & 31, el = t >> 5;
        int e = ec * 8 + el;
        float acc = 0.f;
        for (int d = 0; d < 64; ++d)
            acc += W[(h * 64 + d) * 64 + e] * freqs[(h * 64 + d) * 32 + f];
        Fb[(h * 32 + f) * 64 + e] = __float2bfloat16(acc);
    } else {
        const float* src = (bx < 144) ? Wo : Wv;
        bf16* dst = (bx < 144) ? Wo_bf : Wv_bf;
        int gid = ((bx - 128) & 15) * 256 + t;
        #pragma unroll
        for (int i = 0; i < 2; ++i) {
            int idx4 = gid * 2 + i;
            float4 v = ((const float4*)src)[idx4];
            union { bf16 ob[4]; uint2 u; } pk;
            pk.ob[0] = __float2bfloat16(v.x); pk.ob[1] = __float2bfloat16(v.y);
            pk.ob[2] = __float2bfloat16(v.z); pk.ob[3] = __float2bfloat16(v.w);
            *(uint2*)(dst + idx4 * 4) = pk.u;
        }
    }
}

// ---------------------------------------------------------------------------
// Kernel 2 (fat, MFMA): blocks 0..1023 = encode; 1024..2047 = vproj.
// encode: p[(b,s,m),(h,f)] = atoms @ F^T as [32,64]@[64,256] per block, then
//   sincos + softmax-weighted m-reduction -> q_enc/k_enc bf16.
// vproj: Vt[bh][n=m*64+d][s] = sum_e atoms[b,s,m,e]*Wv[h*64+d][e] via MFMA
//   (A=Wv rows d, B=atoms cols s, K=e), LDS-staged, coalesced stores.
// ---------------------------------------------------------------------------
__global__ __launch_bounds__(256) void encvp(const float* __restrict__ qa_in,
                                             const float* __restrict__ ql,
                                             const float* __restrict__ ka_in,
                                             const float* __restrict__ kl,
                                             const bf16* __restrict__ Fqb,
                                             const bf16* __restrict__ Fkb,
                                             bf16* __restrict__ q_enc,
                                             bf16* __restrict__ k_enc,
                                             const float* __restrict__ va_in,
                                             const bf16* __restrict__ Wv_bf,
                                             bf16* __restrict__ Vt) {
    __shared__ __align__(16) bf16 smem[20480];   // 40KB, unioned per path
    int t = threadIdx.x;
    int w = t >> 6, l = t & 63;
    int quad = l >> 4, r = l & 15;

    if (blockIdx.x < 1024) {
        // ================= encode path =================
        int blk = blockIdx.x;
        int xbase = blk * 4;             // 4 (b,s) groups
        int b = xbase >> 10, s0 = xbase & 1023;
        float* wgtF = (float*)smem;              // [2][32] floats = 128 shorts
        bf16* zL = smem + 256;                   // 2*4*8*64 = 4096 shorts
        int tw = w & 1, nb = (w >> 1) * 8;

        if (t < 64) {
            int which = t >> 5, row = t & 31;
            int si = row >> 3, m = row & 7;
            const float* lwp = (which ? kl : ql) + (size_t)(xbase + si) * 8;
            float lw[8]; float mx = -1e30f;
            #pragma unroll
            for (int j = 0; j < 8; ++j) { lw[j] = lwp[j]; mx = fmaxf(mx, lw[j]); }
            float sm = 0.f;
            #pragma unroll
            for (int j = 0; j < 8; ++j) sm += __expf(lw[j] - mx);
            const float rs = 0.17677669529663687f;  // 1/sqrt(32)
            float osc = which ? rs : rs * 0.125f;
            wgtF[which * 32 + row] = __expf(lw[m] - mx) * (osc / sm);
        }
        __syncthreads();

        for (int which = 0; which < 2; ++which) {
            const float* at = which ? ka_in : qa_in;
            const bf16* Fb = which ? Fkb : Fqb;

            const float* arow = at + ((size_t)(blk * 32 + tw * 16 + r)) * 64 + quad * 8;
            float4 af0 = *(const float4*)(arow);
            float4 af1 = *(const float4*)(arow + 4);
            float4 af2 = *(const float4*)(arow + 32);
            float4 af3 = *(const float4*)(arow + 36);
            short8 a0 = pack8(af0, af1);
            short8 a1 = pack8(af2, af3);

            floatx4 acc[8];
            #pragma unroll
            for (int nt = 0; nt < 8; ++nt) {
                int n = (nb + nt) * 16 + r;
                short8 b0 = *(const short8*)(Fb + n * 64 + quad * 8);
                short8 b1 = *(const short8*)(Fb + n * 64 + quad * 8 + 32);
                floatx4 c = {0.f, 0.f, 0.f, 0.f};
                c = mfma16(a0, b0, c);
                c = mfma16(a1, b1, c);
                acc[nt] = c;
            }

            float wv[4];
            #pragma unroll
            for (int reg = 0; reg < 4; ++reg)
                wv[reg] = wgtF[which * 32 + tw * 16 + quad * 4 + reg];

            int si = tw * 2 + (quad >> 1);
            int iss = quad & 1;
            #pragma unroll
            for (int nt = 0; nt < 8; ++nt) {
                int n = (nb + nt) * 16 + r;
                int h = n >> 5, f = n & 31;
                float zc = 0.f, zs = 0.f;
                #pragma unroll
                for (int reg = 0; reg < 4; ++reg) {
                    float sv, cv;
                    __sincosf(acc[nt][reg], &sv, &cv);
                    zc += wv[reg] * cv;
                    zs += wv[reg] * sv;
                }
                zc += __shfl_xor(zc, 16);
                zs += __shfl_xor(zs, 16);
                float val = iss ? zs : zc;
                zL[((which * 4 + si) * 8 + h) * 64 + f + 32 * iss] = __float2bfloat16(val);
            }
        }
        __syncthreads();

        #pragma unroll
        for (int rep = 0; rep < 2; ++rep) {
            int idx = rep * 256 + t;
            int row = idx >> 3, c = idx & 7;
            int which = row >> 5, si = (row >> 3) & 3, h = row & 7;
            bf16* enc = which ? k_enc : q_enc;
            short8 v = *(const short8*)(zL + row * 64 + c * 8);
            *(short8*)(enc + ((size_t)((b * 8 + h) * 1024 + s0 + si)) * 64 + c * 8) = v;
        }
    } else {
        // ================= vproj path =================
        int vp = blockIdx.x - 1024;
        int bh = vp & 31, sc = vp >> 5;        // 32 s-chunks of 32
        int b = bh >> 3, h = bh & 7;
        bf16* atb = smem;                      // [8m][32s] rows of AT_STRIDE
        bf16* os = smem;                       // reused after barrier: [512n] x VO_STRIDE

        // stage atoms (32 s x 8 m x 64 e fp32) -> bf16 LDS [m][s][e]
        const float* src = va_in + ((size_t)(b * 1024 + sc * 32)) * 512;
        #pragma unroll
        for (int j = 0; j < 16; ++j) {
            int idx4 = j * 256 + t;            // 4096 float4
            float4 v = ((const float4*)src)[idx4];
            int flat = idx4 * 4;               // s*512 + m*64 + e
            int s = flat >> 9, m = (flat >> 6) & 7, e = flat & 63;
            union { bf16 ob[4]; uint2 u; } pk;
            pk.ob[0] = __float2bfloat16(v.x); pk.ob[1] = __float2bfloat16(v.y);
            pk.ob[2] = __float2bfloat16(v.z); pk.ob[3] = __float2bfloat16(v.w);
            *(uint2*)(atb + (m * 32 + s) * AT_STRIDE + e) = pk.u;
        }
        __syncthreads();

        int dhalf = w & 1, sg = w >> 1;
        // A-frags: Wv_bf rows d = dhalf*32 + dt*16 + r (L2-hot)
        short8 aw0[2], aw1[2];
        #pragma unroll
        for (int dt = 0; dt < 2; ++dt) {
            int d = dhalf * 32 + dt * 16 + r;
            aw0[dt] = *(const short8*)(Wv_bf + (h * 64 + d) * 64 + quad * 8);
            aw1[dt] = *(const short8*)(Wv_bf + (h * 64 + d) * 64 + quad * 8 + 32);
        }
        floatx4 acc[8][2];
        #pragma unroll
        for (int m = 0; m < 8; ++m)
            #pragma unroll
            for (int dt = 0; dt < 2; ++dt) acc[m][dt] = (floatx4){0.f, 0.f, 0.f, 0.f};

        #pragma unroll
        for (int m = 0; m < 8; ++m) {
            short8 b0 = *(const short8*)(atb + (m * 32 + sg * 16 + r) * AT_STRIDE + quad * 8);
            short8 b1 = *(const short8*)(atb + (m * 32 + sg * 16 + r) * AT_STRIDE + quad * 8 + 32);
            #pragma unroll
            for (int dt = 0; dt < 2; ++dt) {
                acc[m][dt] = mfma16(aw0[dt], b0, acc[m][dt]);
                acc[m][dt] = mfma16(aw1[dt], b1, acc[m][dt]);
            }
        }
        __syncthreads();   // atb reads done; reuse smem as os

        #pragma unroll
        for (int m = 0; m < 8; ++m)
            #pragma unroll
            for (int dt = 0; dt < 2; ++dt)
                #pragma unroll
                for (int reg = 0; reg < 4; ++reg) {
                    int n = m * 64 + dhalf * 32 + dt * 16 + quad * 4 + reg;
                    os[n * VO_STRIDE + sg * 16 + r] = __float2bfloat16(acc[m][dt][reg]);
                }
        __syncthreads();

        // coalesced store: 512 n rows x 32 s (64B each)
        #pragma unroll
        for (int j = 0; j < 8; ++j) {
            int ch = j * 256 + t;              // 2048 chunks of 8 shorts
            int n = ch >> 2, so = (ch & 3) * 8;
            short8 v = *(const short8*)(os + n * VO_STRIDE + so);
            *(short8*)(Vt + ((size_t)(bh * 512 + n)) * 1024 + sc * 32 + so) = v;
        }
    }
}

// ---------------------------------------------------------------------------
// Kernel 3: attention via MFMA.  1024 blocks (XCD-affine bh mapping), 4 waves.
// 32 q-rows/block; Sc[32][1024] bf16 = 64KB LDS, XOR-swizzled 16B chunks.
// Transposed QK^T (D[k][q]) -> packed b64 swizzled score writes.
// Ring-4 V prefetch in P3 (target ~32 loads in flight per wave).
// ---------------------------------------------------------------------------
__global__ __launch_bounds__(256, 2) void attn_kern(const bf16* __restrict__ q_enc,
                                                    const bf16* __restrict__ k_enc,
                                                    const bf16* __restrict__ Vt,
                                                    bf16* __restrict__ tmp) {
    int n = blockIdx.x;
    int bh = (n & 7) + 8 * (n >> 8);
    int qb = (n >> 3) & 31;
    int b = bh >> 3, h = bh & 7;

    __shared__ __align__(16) bf16 Sc[32 * 1024];   // 64KB
    int t = threadIdx.x;
    int w = t >> 6, l = t & 63;
    int quad = l >> 4, r = l & 15;
    int k7 = r & 7;

    // ---- Phase 1: QK^T transposed (A=K-tile, B=Q-tiles -> D[k][q]).
    const bf16* qbase = q_enc + ((size_t)(bh * 1024 + qb * 32 + r)) * 64 + quad * 8;
    short8 q0 = *(const short8*)(qbase);
    short8 q1 = *(const short8*)(qbase + 32);
    short8 q2 = *(const short8*)(qbase + 16 * 64);
    short8 q3 = *(const short8*)(qbase + 16 * 64 + 32);

    const bf16* kb = k_enc + ((size_t)(bh * 1024 + r)) * 64 + quad * 8;
    short8 kA0 = *(const short8*)(kb + (size_t)(w * 16) * 16 * 64);
    short8 kA1 = *(const short8*)(kb + (size_t)(w * 16) * 16 * 64 + 32);
    short8 kB0 = *(const short8*)(kb + (size_t)(w * 16 + 1) * 16 * 64);
    short8 kB1 = *(const short8*)(kb + (size_t)(w * 16 + 1) * 16 * 64 + 32);

    #pragma unroll
    for (int i = 0; i < 16; ++i) {
        short8 k0 = kA0, k1 = kA1;
        kA0 = kB0; kA1 = kB1;
        if (i < 14) {
            kB0 = *(const short8*)(kb + (size_t)((w * 16 + i + 2) * 16) * 64);
            kB1 = *(const short8*)(kb + (size_t)((w * 16 + i + 2) * 16) * 64 + 32);
        }
        floatx4 c0 = {0.f, 0.f, 0.f, 0.f}, c1 = {0.f, 0.f, 0.f, 0.f};
        c0 = mfma16(k0, q0, c0); c0 = mfma16(k1, q1, c0);
        c1 = mfma16(k0, q2, c1); c1 = mfma16(k1, q3, c1);
        int ktl = w * 16 + i;
        int chunk = ktl * 2 + (quad >> 1);
        int sw = ((chunk ^ k7) << 3) + (quad & 1) * 4;
        union { uint2 u; bf16 bb[4]; } p0, p1;
        #pragma unroll
        for (int reg = 0; reg < 4; ++reg) {
            p0.bb[reg] = __float2bfloat16(c0[reg]);
            p1.bb[reg] = __float2bfloat16(c1[reg]);
        }
        *(uint2*)(Sc + r * 1024 + sw) = p0.u;
        *(uint2*)(Sc + (r + 16) * 1024 + sw) = p1.u;
    }
    __syncthreads();

    // ---- Phase 2: softmax, normalized in place (wave w: rows w*8..w*8+7)
    for (int i = 0; i < 8; ++i) {
        int row = w * 8 + i;
        int key = row & 7;
        bf16* rowp = Sc + row * 1024;
        int p0 = ((2 * l) ^ key) << 3;
        int p1 = ((2 * l + 1) ^ key) << 3;
        union { short8 s; unsigned short u[8]; } v0, v1;
        v0.s = *(const short8*)(rowp + p0);
        v1.s = *(const short8*)(rowp + p1);
        float f[16];
        #pragma unroll
        for (int j = 0; j < 8; ++j) { f[j] = us2f(v0.u[j]); f[8 + j] = us2f(v1.u[j]); }
        float mx = -1e30f;
        #pragma unroll
        for (int j = 0; j < 16; ++j) mx = fmaxf(mx, f[j]);
        #pragma unroll
        for (int off = 32; off; off >>= 1) mx = fmaxf(mx, __shfl_xor(mx, off));
        float sm = 0.f;
        #pragma unroll
        for (int j = 0; j < 16; ++j) { f[j] = __expf(f[j] - mx); sm += f[j]; }
        #pragma unroll
        for (int off = 32; off; off >>= 1) sm += __shfl_xor(sm, off);
        float inv = 1.f / sm;
        #pragma unroll
        for (int j = 0; j < 8; ++j) {
            v0.u[j] = (unsigned short)(__bfloat16_as_ushort(__float2bfloat16(f[j] * inv)));
            v1.u[j] = (unsigned short)(__bfloat16_as_ushort(__float2bfloat16(f[8 + j] * inv)));
        }
        *(short8*)(rowp + p0) = v0.s;
        *(short8*)(rowp + p1) = v1.s;
    }
    __syncthreads();

    // ---- Phase 3: P@V.  wave w: n-cols [w*128, w*128+128), both 16-row tiles.
    // Ring-4 prefetch: slots are compile-time constants under full unroll.
    floatx4 acc0[8], acc1[8];
    #pragma unroll
    for (int nt = 0; nt < 8; ++nt) {
        acc0[nt] = (floatx4){0.f, 0.f, 0.f, 0.f};
        acc1[nt] = (floatx4){0.f, 0.f, 0.f, 0.f};
    }
    const bf16* vbase = Vt + ((size_t)(bh * 512 + w * 128 + r)) * 1024 + quad * 8;
    short8 vb[4][8];
    #pragma unroll
    for (int p = 0; p < 3; ++p)
        #pragma unroll
        for (int nt = 0; nt < 8; ++nt)
            vb[p][nt] = *(const short8*)(vbase + nt * 16384 + p * 32);

    #pragma unroll
    for (int ks = 0; ks < 32; ++ks) {
        if (ks < 29) {
            #pragma unroll
            for (int nt = 0; nt < 8; ++nt)
                vb[(ks + 3) & 3][nt] = *(const short8*)(vbase + nt * 16384 + (ks + 3) * 32);
        }
        int pc = (((ks * 4 + quad) ^ k7) << 3);
        short8 pa0 = *(const short8*)(Sc + r * 1024 + pc);
        short8 pa1 = *(const short8*)(Sc + (16 + r) * 1024 + pc);
        #pragma unroll
        for (int nt = 0; nt < 8; ++nt) {
            acc0[nt] = mfma16(pa0, vb[ks & 3][nt], acc0[nt]);
            acc1[nt] = mfma16(pa1, vb[ks & 3][nt], acc1[nt]);
        }
    }
    __syncthreads();   // all Sc reads done; reuse for output staging

    bf16* Ob = Sc;
    #pragma unroll
    for (int nt = 0; nt < 8; ++nt)
        #pragma unroll
        for (int reg = 0; reg < 4; ++reg) {
            int col = w * 128 + nt * 16 + r;
            Ob[(quad * 4 + reg) * OB_STRIDE + col] = __float2bfloat16(acc0[nt][reg]);
            Ob[(quad * 4 + reg + 16) * OB_STRIDE + col] = __float2bfloat16(acc1[nt][reg]);
        }
    __syncthreads();

    // coalesced store: 32 rows x 512 cols bf16 -> tmp[b][q][m][h][d]
    #pragma unroll
    for (int i = 0; i < 8; ++i) {
        int c = i * 256 + t;
        int row = c >> 6, j = c & 63;
        int m = j >> 3, d0 = (j & 7) * 8;
        short8 v = *(const short8*)(Ob + row * OB_STRIDE + j * 8);
        *(short8*)(tmp + ((((size_t)(b * 1024 + qb * 32 + row) * 8 + m) * 8 + h) * 64 + d0)) = v;
    }
}

// ---------------------------------------------------------------------------
// Kernel 4 (MFMA): out_atoms[row, o] = tmp[row, :512] @ Wo_bf[o, :512]
// ---------------------------------------------------------------------------
__global__ __launch_bounds__(256) void finalize(const bf16* __restrict__ tmp,
                                                const bf16* __restrict__ Wo_bf,
                                                const float* __restrict__ Ww,
                                                const float* __restrict__ ql,
                                                float* __restrict__ out) {
    __shared__ __align__(16) float Os[64][OS_STRIDE];   // 17.4 KB
    __shared__ float fs[8][64];
    int t = threadIdx.x;
    int w = t >> 6, l = t & 63;
    int quad = l >> 4, r = l & 15;
    size_t rowbase = (size_t)blockIdx.x * 64;

    floatx4 acc[4];
    #pragma unroll
    for (int nt = 0; nt < 4; ++nt) acc[nt] = (floatx4){0.f, 0.f, 0.f, 0.f};

    const bf16* arow = tmp + (rowbase + w * 16 + r) * 512 + quad * 8;
    const bf16* brow = Wo_bf + r * 512 + quad * 8;

    for (int ks = 0; ks < 16; ++ks) {
        short8 a = *(const short8*)(arow + ks * 32);
        #pragma unroll
        for (int nt = 0; nt < 4; ++nt) {
            short8 bb = *(const short8*)(brow + nt * 16 * 512 + ks * 32);
            acc[nt] = mfma16(a, bb, acc[nt]);
        }
    }
    #pragma unroll
    for (int nt = 0; nt < 4; ++nt)
        #pragma unroll
        for (int reg = 0; reg < 4; ++reg)
            Os[w * 16 + quad * 4 + reg][nt * 16 + r] = acc[nt][reg];
    __syncthreads();

    #pragma unroll
    for (int i = 0; i < 4; ++i) {
        int ch = i * 256 + t;
        int rr = ch >> 4, c4 = (ch & 15) * 4;
        float4 v = *(const float4*)&Os[rr][c4];
        *(float4*)(out + (rowbase + rr) * 64 + c4) = v;
    }

    {
        int g = t >> 5, oo = (t & 31) * 2;
        float f0 = 0.f, f1 = 0.f;
        #pragma unroll
        for (int m = 0; m < 8; ++m) {
            f0 += Os[g * 8 + m][oo];
            f1 += Os[g * 8 + m][oo + 1];
        }
        fs[g][oo] = f0 * 0.125f;
        fs[g][oo + 1] = f1 * 0.125f;
    }
    __syncthreads();

    if (t < 64) {
        int g = t >> 3, mm = t & 7;
        size_t x = (size_t)blockIdx.x * 8 + g;
        float nl = ql[x * 8 + mm];
        #pragma unroll
        for (int o = 0; o < 64; ++o) nl += fs[g][o] * Ww[mm * 64 + o];
        out[(size_t)CB * CS * CM * CD + x * 8 + mm] = nl;
    }
}

// ---------------------------------------------------------------------------
extern "C" void kernel_launch(void* const* d_in, const int* in_sizes, int n_in,
                              void* d_out, int out_size, void* d_ws, size_t ws_size,
                              hipStream_t stream) {
    const float* q_atoms = (const float*)d_in[0];
    const float* q_logw  = (const float*)d_in[1];
    const float* k_atoms = (const float*)d_in[2];
    const float* k_logw  = (const float*)d_in[3];
    const float* v_atoms = (const float*)d_in[4];
    // d_in[5] = v_logw (unused by the reference)
    const float* Wq = (const float*)d_in[6];
    const float* Wk = (const float*)d_in[7];
    const float* Wv = (const float*)d_in[8];
    const float* Wo = (const float*)d_in[9];
    const float* Ww = (const float*)d_in[10];
    const float* freqs = (const float*)d_in[11];

    // ws layout (all bf16): Fqb[16384] | Fkb[16384] | q_enc[2097152]
    //   | k_enc[2097152] | Vt[16777216] | tmp[16777216] | Wo_bf[32768] | Wv_bf[32768]
    bf16* Fqb = (bf16*)d_ws;
    bf16* Fkb = Fqb + 16384;
    bf16* q_enc = Fkb + 16384;
    bf16* k_enc = q_enc + 2097152;
    bf16* Vt = k_enc + 2097152;
    bf16* tmp = Vt + 16777216;
    bf16* Wo_bf = tmp + 16777216;
    bf16* Wv_bf = Wo_bf + 32768;
    float* out = (float*)d_out;

    prep<<<160, 256, 0, stream>>>(Wq, Wk, freqs, Wo, Wv, Fqb, Fkb, Wo_bf, Wv_bf);
    encvp<<<2048, 256, 0, stream>>>(q_atoms, q_logw, k_atoms, k_logw,
                                    Fqb, Fkb, q_enc, k_enc,
                                    v_atoms, Wv_bf, Vt);
    attn_kern<<<1024, 256, 0, stream>>>(q_enc, k_enc, Vt, tmp);
    finalize<<<CB * CS / 8, 256, 0, stream>>>(tmp, Wo_bf, Ww, q_logw, out);
}

// Round 10
// 286.517 us; speedup vs baseline: 1.5711x; 1.0039x over previous
//
#include <hip/hip_runtime.h>
#include <hip/hip_bf16.h>

typedef __hip_bfloat16 bf16;
typedef __attribute__((ext_vector_type(8))) short short8;
typedef __attribute__((ext_vector_type(4))) float floatx4;

// Problem constants: B=4, S=1024, M=8, D=64, H=8, NF=32, HD=512
#define CB 4
#define CS 1024
#define CM 8
#define CD 64
#define CH 8
#define CNF 32
#define CHD 512

#define OB_STRIDE 520    // attn epilogue staging stride (bf16): 16B-aligned rows
#define OS_STRIDE 68     // finalize staging stride (fp32)
#define AT_STRIDE 72     // vproj atoms LDS row stride (shorts): 36 words -> bank spread
#define VO_STRIDE 40     // vproj output staging stride (shorts)

__device__ __forceinline__ float b2f(bf16 x) { return __bfloat162float(x); }
__device__ __forceinline__ float us2f(unsigned short u) {
    union { unsigned int i; float f; } v; v.i = ((unsigned int)u) << 16; return v.f;
}
__device__ __forceinline__ floatx4 mfma16(short8 a, short8 b, floatx4 c) {
    return __builtin_amdgcn_mfma_f32_16x16x32_bf16(a, b, c, 0, 0, 0);
}
__device__ __forceinline__ short8 pack8(float4 x, float4 y) {
    union { short8 s; bf16 b[8]; } u;
    u.b[0] = __float2bfloat16(x.x); u.b[1] = __float2bfloat16(x.y);
    u.b[2] = __float2bfloat16(x.z); u.b[3] = __float2bfloat16(x.w);
    u.b[4] = __float2bfloat16(y.x); u.b[5] = __float2bfloat16(y.y);
    u.b[6] = __float2bfloat16(y.z); u.b[7] = __float2bfloat16(y.w);
    return u.s;
}

// ---------------------------------------------------------------------------
// Kernel 1 (prep): 160 blocks.
//   blocks 0..127: Fb[which][n=h*32+f][e] = sum_d W[h*64+d][e]*freqs[h][d][f]
//   blocks 128..143: Wo fp32 -> bf16;  144..159: Wv fp32 -> bf16
// ---------------------------------------------------------------------------
__global__ __launch_bounds__(256) void prep(const float* __restrict__ Wq,
                                            const float* __restrict__ Wk,
                                            const float* __restrict__ freqs,
                                            const float* __restrict__ Wo,
                                            const float* __restrict__ Wv,
                                            bf16* __restrict__ Fqb,
                                            bf16* __restrict__ Fkb,
                                            bf16* __restrict__ Wo_bf,
                                            bf16* __restrict__ Wv_bf) {
    int bx = blockIdx.x, t = threadIdx.x;
    if (bx < 128) {
        int which = bx >> 6, h = (bx >> 3) & 7, ec = bx & 7;
        const float* W = which ? Wk : Wq;
        bf16* Fb = which ? Fkb : Fqb;
        int f = t & 31, el = t >> 5;
        int e = ec * 8 + el;
        float acc = 0.f;
        for (int d = 0; d < 64; ++d)
            acc += W[(h * 64 + d) * 64 + e] * freqs[(h * 64 + d) * 32 + f];
        Fb[(h * 32 + f) * 64 + e] = __float2bfloat16(acc);
    } else {
        const float* src = (bx < 144) ? Wo : Wv;
        bf16* dst = (bx < 144) ? Wo_bf : Wv_bf;
        int gid = ((bx - 128) & 15) * 256 + t;
        #pragma unroll
        for (int i = 0; i < 2; ++i) {
            int idx4 = gid * 2 + i;
            float4 v = ((const float4*)src)[idx4];
            union { bf16 ob[4]; uint2 u; } pk;
            pk.ob[0] = __float2bfloat16(v.x); pk.ob[1] = __float2bfloat16(v.y);
            pk.ob[2] = __float2bfloat16(v.z); pk.ob[3] = __float2bfloat16(v.w);
            *(uint2*)(dst + idx4 * 4) = pk.u;
        }
    }
}

// ---------------------------------------------------------------------------
// Kernel 2 (fat, MFMA): blocks 0..1023 = encode; 1024..2047 = vproj.
// ---------------------------------------------------------------------------
__global__ __launch_bounds__(256) void encvp(const float* __restrict__ qa_in,
                                             const float* __restrict__ ql,
                                             const float* __restrict__ ka_in,
                                             const float* __restrict__ kl,
                                             const bf16* __restrict__ Fqb,
                                             const bf16* __restrict__ Fkb,
                                             bf16* __restrict__ q_enc,
                                             bf16* __restrict__ k_enc,
                                             const float* __restrict__ va_in,
                                             const bf16* __restrict__ Wv_bf,
                                             bf16* __restrict__ Vt) {
    __shared__ __align__(16) bf16 smem[20480];   // 40KB, unioned per path
    int t = threadIdx.x;
    int w = t >> 6, l = t & 63;
    int quad = l >> 4, r = l & 15;

    if (blockIdx.x < 1024) {
        // ================= encode path =================
        int blk = blockIdx.x;
        int xbase = blk * 4;             // 4 (b,s) groups
        int b = xbase >> 10, s0 = xbase & 1023;
        float* wgtF = (float*)smem;              // [2][32] floats
        bf16* zL = smem + 256;                   // 4096 shorts
        int tw = w & 1, nb = (w >> 1) * 8;

        if (t < 64) {
            int which = t >> 5, row = t & 31;
            int si = row >> 3, m = row & 7;
            const float* lwp = (which ? kl : ql) + (size_t)(xbase + si) * 8;
            float lw[8]; float mx = -1e30f;
            #pragma unroll
            for (int j = 0; j < 8; ++j) { lw[j] = lwp[j]; mx = fmaxf(mx, lw[j]); }
            float sm = 0.f;
            #pragma unroll
            for (int j = 0; j < 8; ++j) sm += __expf(lw[j] - mx);
            const float rs = 0.17677669529663687f;  // 1/sqrt(32)
            float osc = which ? rs : rs * 0.125f;
            wgtF[which * 32 + row] = __expf(lw[m] - mx) * (osc / sm);
        }
        __syncthreads();

        for (int which = 0; which < 2; ++which) {
            const float* at = which ? ka_in : qa_in;
            const bf16* Fb = which ? Fkb : Fqb;

            const float* arow = at + ((size_t)(blk * 32 + tw * 16 + r)) * 64 + quad * 8;
            float4 af0 = *(const float4*)(arow);
            float4 af1 = *(const float4*)(arow + 4);
            float4 af2 = *(const float4*)(arow + 32);
            float4 af3 = *(const float4*)(arow + 36);
            short8 a0 = pack8(af0, af1);
            short8 a1 = pack8(af2, af3);

            floatx4 acc[8];
            #pragma unroll
            for (int nt = 0; nt < 8; ++nt) {
                int n = (nb + nt) * 16 + r;
                short8 b0 = *(const short8*)(Fb + n * 64 + quad * 8);
                short8 b1 = *(const short8*)(Fb + n * 64 + quad * 8 + 32);
                floatx4 c = {0.f, 0.f, 0.f, 0.f};
                c = mfma16(a0, b0, c);
                c = mfma16(a1, b1, c);
                acc[nt] = c;
            }

            float wv[4];
            #pragma unroll
            for (int reg = 0; reg < 4; ++reg)
                wv[reg] = wgtF[which * 32 + tw * 16 + quad * 4 + reg];

            int si = tw * 2 + (quad >> 1);
            int iss = quad & 1;
            #pragma unroll
            for (int nt = 0; nt < 8; ++nt) {
                int n = (nb + nt) * 16 + r;
                int h = n >> 5, f = n & 31;
                float zc = 0.f, zs = 0.f;
                #pragma unroll
                for (int reg = 0; reg < 4; ++reg) {
                    float sv, cv;
                    __sincosf(acc[nt][reg], &sv, &cv);
                    zc += wv[reg] * cv;
                    zs += wv[reg] * sv;
                }
                zc += __shfl_xor(zc, 16);
                zs += __shfl_xor(zs, 16);
                float val = iss ? zs : zc;
                zL[((which * 4 + si) * 8 + h) * 64 + f + 32 * iss] = __float2bfloat16(val);
            }
        }
        __syncthreads();

        #pragma unroll
        for (int rep = 0; rep < 2; ++rep) {
            int idx = rep * 256 + t;
            int row = idx >> 3, c = idx & 7;
            int which = row >> 5, si = (row >> 3) & 3, h = row & 7;
            bf16* enc = which ? k_enc : q_enc;
            short8 v = *(const short8*)(zL + row * 64 + c * 8);
            *(short8*)(enc + ((size_t)((b * 8 + h) * 1024 + s0 + si)) * 64 + c * 8) = v;
        }
    } else {
        // ================= vproj path =================
        int vp = blockIdx.x - 1024;
        int bh = vp & 31, sc = vp >> 5;
        int b = bh >> 3, h = bh & 7;
        bf16* atb = smem;
        bf16* os = smem;

        const float* src = va_in + ((size_t)(b * 1024 + sc * 32)) * 512;
        #pragma unroll
        for (int j = 0; j < 16; ++j) {
            int idx4 = j * 256 + t;
            float4 v = ((const float4*)src)[idx4];
            int flat = idx4 * 4;
            int s = flat >> 9, m = (flat >> 6) & 7, e = flat & 63;
            union { bf16 ob[4]; uint2 u; } pk;
            pk.ob[0] = __float2bfloat16(v.x); pk.ob[1] = __float2bfloat16(v.y);
            pk.ob[2] = __float2bfloat16(v.z); pk.ob[3] = __float2bfloat16(v.w);
            *(uint2*)(atb + (m * 32 + s) * AT_STRIDE + e) = pk.u;
        }
        __syncthreads();

        int dhalf = w & 1, sg = w >> 1;
        short8 aw0[2], aw1[2];
        #pragma unroll
        for (int dt = 0; dt < 2; ++dt) {
            int d = dhalf * 32 + dt * 16 + r;
            aw0[dt] = *(const short8*)(Wv_bf + (h * 64 + d) * 64 + quad * 8);
            aw1[dt] = *(const short8*)(Wv_bf + (h * 64 + d) * 64 + quad * 8 + 32);
        }
        floatx4 acc[8][2];
        #pragma unroll
        for (int m = 0; m < 8; ++m)
            #pragma unroll
            for (int dt = 0; dt < 2; ++dt) acc[m][dt] = (floatx4){0.f, 0.f, 0.f, 0.f};

        #pragma unroll
        for (int m = 0; m < 8; ++m) {
            short8 b0 = *(const short8*)(atb + (m * 32 + sg * 16 + r) * AT_STRIDE + quad * 8);
            short8 b1 = *(const short8*)(atb + (m * 32 + sg * 16 + r) * AT_STRIDE + quad * 8 + 32);
            #pragma unroll
            for (int dt = 0; dt < 2; ++dt) {
                acc[m][dt] = mfma16(aw0[dt], b0, acc[m][dt]);
                acc[m][dt] = mfma16(aw1[dt], b1, acc[m][dt]);
            }
        }
        __syncthreads();

        #pragma unroll
        for (int m = 0; m < 8; ++m)
            #pragma unroll
            for (int dt = 0; dt < 2; ++dt)
                #pragma unroll
                for (int reg = 0; reg < 4; ++reg) {
                    int n = m * 64 + dhalf * 32 + dt * 16 + quad * 4 + reg;
                    os[n * VO_STRIDE + sg * 16 + r] = __float2bfloat16(acc[m][dt][reg]);
                }
        __syncthreads();

        #pragma unroll
        for (int j = 0; j < 8; ++j) {
            int ch = j * 256 + t;
            int n = ch >> 2, so = (ch & 3) * 8;
            short8 v = *(const short8*)(os + n * VO_STRIDE + so);
            *(short8*)(Vt + ((size_t)(bh * 512 + n)) * 1024 + sc * 32 + so) = v;
        }
    }
}

// ---------------------------------------------------------------------------
// Kernel 3: attention via MFMA.  1024 blocks (XCD-affine bh mapping), now
// 512 threads = 8 waves (TLP for latency: 2 blocks/CU -> 16 waves/CU).
// 32 q-rows/block; Sc[32][1024] bf16 = 64KB LDS, XOR-swizzled 16B chunks.
// Transposed QK^T (D[k][q]) -> packed b64 swizzled score writes.
// ---------------------------------------------------------------------------
__global__ __launch_bounds__(512, 4) void attn_kern(const bf16* __restrict__ q_enc,
                                                    const bf16* __restrict__ k_enc,
                                                    const bf16* __restrict__ Vt,
                                                    bf16* __restrict__ tmp) {
    int n = blockIdx.x;
    int bh = (n & 7) + 8 * (n >> 8);
    int qb = (n >> 3) & 31;
    int b = bh >> 3, h = bh & 7;

    __shared__ __align__(16) bf16 Sc[32 * 1024];   // 64KB
    int t = threadIdx.x;
    int w = t >> 6, l = t & 63;         // w in [0,8)
    int quad = l >> 4, r = l & 15;
    int k7 = r & 7;

    // ---- Phase 1: QK^T transposed (A=K-tile, B=Q-tiles -> D[k][q]).
    const bf16* qbase = q_enc + ((size_t)(bh * 1024 + qb * 32 + r)) * 64 + quad * 8;
    short8 q0 = *(const short8*)(qbase);
    short8 q1 = *(const short8*)(qbase + 32);
    short8 q2 = *(const short8*)(qbase + 16 * 64);
    short8 q3 = *(const short8*)(qbase + 16 * 64 + 32);

    // wave w handles k-tiles w*8 .. w*8+7; distance-2 prefetch
    const bf16* kb = k_enc + ((size_t)(bh * 1024 + r)) * 64 + quad * 8;
    short8 kA0 = *(const short8*)(kb + (size_t)(w * 8) * 16 * 64);
    short8 kA1 = *(const short8*)(kb + (size_t)(w * 8) * 16 * 64 + 32);
    short8 kB0 = *(const short8*)(kb + (size_t)(w * 8 + 1) * 16 * 64);
    short8 kB1 = *(const short8*)(kb + (size_t)(w * 8 + 1) * 16 * 64 + 32);

    #pragma unroll
    for (int i = 0; i < 8; ++i) {
        short8 k0 = kA0, k1 = kA1;
        kA0 = kB0; kA1 = kB1;
        if (i < 6) {
            kB0 = *(const short8*)(kb + (size_t)((w * 8 + i + 2) * 16) * 64);
            kB1 = *(const short8*)(kb + (size_t)((w * 8 + i + 2) * 16) * 64 + 32);
        }
        floatx4 c0 = {0.f, 0.f, 0.f, 0.f}, c1 = {0.f, 0.f, 0.f, 0.f};
        c0 = mfma16(k0, q0, c0); c0 = mfma16(k1, q1, c0);
        c1 = mfma16(k0, q2, c1); c1 = mfma16(k1, q3, c1);
        int ktl = w * 8 + i;
        int chunk = ktl * 2 + (quad >> 1);
        int sw = ((chunk ^ k7) << 3) + (quad & 1) * 4;
        union { uint2 u; bf16 bb[4]; } p0, p1;
        #pragma unroll
        for (int reg = 0; reg < 4; ++reg) {
            p0.bb[reg] = __float2bfloat16(c0[reg]);
            p1.bb[reg] = __float2bfloat16(c1[reg]);
        }
        *(uint2*)(Sc + r * 1024 + sw) = p0.u;
        *(uint2*)(Sc + (r + 16) * 1024 + sw) = p1.u;
    }
    __syncthreads();

    // ---- Phase 2: softmax, normalized in place (wave w: rows w*4..w*4+3)
    for (int i = 0; i < 4; ++i) {
        int row = w * 4 + i;
        int key = row & 7;
        bf16* rowp = Sc + row * 1024;
        int p0 = ((2 * l) ^ key) << 3;
        int p1 = ((2 * l + 1) ^ key) << 3;
        union { short8 s; unsigned short u[8]; } v0, v1;
        v0.s = *(const short8*)(rowp + p0);
        v1.s = *(const short8*)(rowp + p1);
        float f[16];
        #pragma unroll
        for (int j = 0; j < 8; ++j) { f[j] = us2f(v0.u[j]); f[8 + j] = us2f(v1.u[j]); }
        float mx = -1e30f;
        #pragma unroll
        for (int j = 0; j < 16; ++j) mx = fmaxf(mx, f[j]);
        #pragma unroll
        for (int off = 32; off; off >>= 1) mx = fmaxf(mx, __shfl_xor(mx, off));
        float sm = 0.f;
        #pragma unroll
        for (int j = 0; j < 16; ++j) { f[j] = __expf(f[j] - mx); sm += f[j]; }
        #pragma unroll
        for (int off = 32; off; off >>= 1) sm += __shfl_xor(sm, off);
        float inv = 1.f / sm;
        #pragma unroll
        for (int j = 0; j < 8; ++j) {
            v0.u[j] = (unsigned short)(__bfloat16_as_ushort(__float2bfloat16(f[j] * inv)));
            v1.u[j] = (unsigned short)(__bfloat16_as_ushort(__float2bfloat16(f[8 + j] * inv)));
        }
        *(short8*)(rowp + p0) = v0.s;
        *(short8*)(rowp + p1) = v1.s;
    }
    __syncthreads();

    // ---- Phase 3: P@V.  wave w: n-cols [w*64, w*64+64) = 4 n-tiles, both
    // 16-row tiles.  Distance-2 prefetch (3 live batches of 4 V-fragments).
    floatx4 acc0[4], acc1[4];
    #pragma unroll
    for (int nt = 0; nt < 4; ++nt) {
        acc0[nt] = (floatx4){0.f, 0.f, 0.f, 0.f};
        acc1[nt] = (floatx4){0.f, 0.f, 0.f, 0.f};
    }
    const bf16* vbase = Vt + ((size_t)(bh * 512 + w * 64 + r)) * 1024 + quad * 8;
    short8 vA[4], vB[4], vC[4];
    #pragma unroll
    for (int nt = 0; nt < 4; ++nt) vA[nt] = *(const short8*)(vbase + nt * 16384);
    #pragma unroll
    for (int nt = 0; nt < 4; ++nt) vB[nt] = *(const short8*)(vbase + nt * 16384 + 32);

    #pragma unroll
    for (int ks = 0; ks < 32; ++ks) {
        if (ks < 30) {
            #pragma unroll
            for (int nt = 0; nt < 4; ++nt)
                vC[nt] = *(const short8*)(vbase + nt * 16384 + (ks + 2) * 32);
        }
        int pc = (((ks * 4 + quad) ^ k7) << 3);
        short8 pa0 = *(const short8*)(Sc + r * 1024 + pc);
        short8 pa1 = *(const short8*)(Sc + (16 + r) * 1024 + pc);
        #pragma unroll
        for (int nt = 0; nt < 4; ++nt) {
            acc0[nt] = mfma16(pa0, vA[nt], acc0[nt]);
            acc1[nt] = mfma16(pa1, vA[nt], acc1[nt]);
        }
        #pragma unroll
        for (int nt = 0; nt < 4; ++nt) { vA[nt] = vB[nt]; vB[nt] = vC[nt]; }
    }
    __syncthreads();   // all Sc reads done; reuse for output staging

    bf16* Ob = Sc;
    #pragma unroll
    for (int nt = 0; nt < 4; ++nt)
        #pragma unroll
        for (int reg = 0; reg < 4; ++reg) {
            int col = w * 64 + nt * 16 + r;
            Ob[(quad * 4 + reg) * OB_STRIDE + col] = __float2bfloat16(acc0[nt][reg]);
            Ob[(quad * 4 + reg + 16) * OB_STRIDE + col] = __float2bfloat16(acc1[nt][reg]);
        }
    __syncthreads();

    // coalesced store: 32 rows x 512 cols bf16 -> tmp[b][q][m][h][d]
    #pragma unroll
    for (int i = 0; i < 4; ++i) {
        int c = i * 512 + t;          // 0..2047 chunks of 8 bf16
        int row = c >> 6, j = c & 63;
        int m = j >> 3, d0 = (j & 7) * 8;
        short8 v = *(const short8*)(Ob + row * OB_STRIDE + j * 8);
        *(short8*)(tmp + ((((size_t)(b * 1024 + qb * 32 + row) * 8 + m) * 8 + h) * 64 + d0)) = v;
    }
}

// ---------------------------------------------------------------------------
// Kernel 4 (MFMA): out_atoms[row, o] = tmp[row, :512] @ Wo_bf[o, :512]
// ---------------------------------------------------------------------------
__global__ __launch_bounds__(256) void finalize(const bf16* __restrict__ tmp,
                                                const bf16* __restrict__ Wo_bf,
                                                const float* __restrict__ Ww,
                                                const float* __restrict__ ql,
                                                float* __restrict__ out) {
    __shared__ __align__(16) float Os[64][OS_STRIDE];   // 17.4 KB
    __shared__ float fs[8][64];
    int t = threadIdx.x;
    int w = t >> 6, l = t & 63;
    int quad = l >> 4, r = l & 15;
    size_t rowbase = (size_t)blockIdx.x * 64;

    floatx4 acc[4];
    #pragma unroll
    for (int nt = 0; nt < 4; ++nt) acc[nt] = (floatx4){0.f, 0.f, 0.f, 0.f};

    const bf16* arow = tmp + (rowbase + w * 16 + r) * 512 + quad * 8;
    const bf16* brow = Wo_bf + r * 512 + quad * 8;

    for (int ks = 0; ks < 16; ++ks) {
        short8 a = *(const short8*)(arow + ks * 32);
        #pragma unroll
        for (int nt = 0; nt < 4; ++nt) {
            short8 bb = *(const short8*)(brow + nt * 16 * 512 + ks * 32);
            acc[nt] = mfma16(a, bb, acc[nt]);
        }
    }
    #pragma unroll
    for (int nt = 0; nt < 4; ++nt)
        #pragma unroll
        for (int reg = 0; reg < 4; ++reg)
            Os[w * 16 + quad * 4 + reg][nt * 16 + r] = acc[nt][reg];
    __syncthreads();

    #pragma unroll
    for (int i = 0; i < 4; ++i) {
        int ch = i * 256 + t;
        int rr = ch >> 4, c4 = (ch & 15) * 4;
        float4 v = *(const float4*)&Os[rr][c4];
        *(float4*)(out + (rowbase + rr) * 64 + c4) = v;
    }

    {
        int g = t >> 5, oo = (t & 31) * 2;
        float f0 = 0.f, f1 = 0.f;
        #pragma unroll
        for (int m = 0; m < 8; ++m) {
            f0 += Os[g * 8 + m][oo];
            f1 += Os[g * 8 + m][oo + 1];
        }
        fs[g][oo] = f0 * 0.125f;
        fs[g][oo + 1] = f1 * 0.125f;
    }
    __syncthreads();

    if (t < 64) {
        int g = t >> 3, mm = t & 7;
        size_t x = (size_t)blockIdx.x * 8 + g;
        float nl = ql[x * 8 + mm];
        #pragma unroll
        for (int o = 0; o < 64; ++o) nl += fs[g][o] * Ww[mm * 64 + o];
        out[(size_t)CB * CS * CM * CD + x * 8 + mm] = nl;
    }
}

// ---------------------------------------------------------------------------
extern "C" void kernel_launch(void* const* d_in, const int* in_sizes, int n_in,
                              void* d_out, int out_size, void* d_ws, size_t ws_size,
                              hipStream_t stream) {
    const float* q_atoms = (const float*)d_in[0];
    const float* q_logw  = (const float*)d_in[1];
    const float* k_atoms = (const float*)d_in[2];
    const float* k_logw  = (const float*)d_in[3];
    const float* v_atoms = (const float*)d_in[4];
    // d_in[5] = v_logw (unused by the reference)
    const float* Wq = (const float*)d_in[6];
    const float* Wk = (const float*)d_in[7];
    const float* Wv = (const float*)d_in[8];
    const float* Wo = (const float*)d_in[9];
    const float* Ww = (const float*)d_in[10];
    const float* freqs = (const float*)d_in[11];

    // ws layout (all bf16): Fqb[16384] | Fkb[16384] | q_enc[2097152]
    //   | k_enc[2097152] | Vt[16777216] | tmp[16777216] | Wo_bf[32768] | Wv_bf[32768]
    bf16* Fqb = (bf16*)d_ws;
    bf16* Fkb = Fqb + 16384;
    bf16* q_enc = Fkb + 16384;
    bf16* k_enc = q_enc + 2097152;
    bf16* Vt = k_enc + 2097152;
    bf16* tmp = Vt + 16777216;
    bf16* Wo_bf = tmp + 16777216;
    bf16* Wv_bf = Wo_bf + 32768;
    float* out = (float*)d_out;

    prep<<<160, 256, 0, stream>>>(Wq, Wk, freqs, Wo, Wv, Fqb, Fkb, Wo_bf, Wv_bf);
    encvp<<<2048, 256, 0, stream>>>(q_atoms, q_logw, k_atoms, k_logw,
                                    Fqb, Fkb, q_enc, k_enc,
                                    v_atoms, Wv_bf, Vt);
    attn_kern<<<1024, 512, 0, stream>>>(q_enc, k_enc, Vt, tmp);
    finalize<<<CB * CS / 8, 256, 0, stream>>>(tmp, Wo_bf, Ww, q_logw, out);
}

// Round 11
// 203.060 us; speedup vs baseline: 2.2168x; 1.4110x over previous
//
#include <hip/hip_runtime.h>
#include <hip/hip_bf16.h>

typedef __hip_bfloat16 bf16;
typedef __attribute__((ext_vector_type(8))) short short8;
typedef __attribute__((ext_vector_type(4))) float floatx4;

// Problem constants: B=4, S=1024, M=8, D=64, H=8, NF=32, HD=512
#define CB 4
#define CS 1024
#define CM 8
#define CD 64
#define CH 8
#define CNF 32
#define CHD 512

#define OB_STRIDE 520    // attn epilogue staging stride (bf16): 16B-aligned rows
#define OS_STRIDE 68     // finalize staging stride (fp32)
#define AT_STRIDE 72     // vproj atoms LDS row stride (shorts)
#define VO_STRIDE 40     // vproj output staging stride (shorts)

__device__ __forceinline__ float b2f(bf16 x) { return __bfloat162float(x); }
__device__ __forceinline__ float us2f(unsigned short u) {
    union { unsigned int i; float f; } v; v.i = ((unsigned int)u) << 16; return v.f;
}
__device__ __forceinline__ floatx4 mfma16(short8 a, short8 b, floatx4 c) {
    return __builtin_amdgcn_mfma_f32_16x16x32_bf16(a, b, c, 0, 0, 0);
}
__device__ __forceinline__ short8 pack8(float4 x, float4 y) {
    union { short8 s; bf16 b[8]; } u;
    u.b[0] = __float2bfloat16(x.x); u.b[1] = __float2bfloat16(x.y);
    u.b[2] = __float2bfloat16(x.z); u.b[3] = __float2bfloat16(x.w);
    u.b[4] = __float2bfloat16(y.x); u.b[5] = __float2bfloat16(y.y);
    u.b[6] = __float2bfloat16(y.z); u.b[7] = __float2bfloat16(y.w);
    return u.s;
}

// Fragment-order layouts (lane l = quad*16 + r):
//   kf/qf[bh][kt=s>>4][half=f>>5][l*8] : chunk holds row kt*16+r, f half*32+quad*8..+8
//   Vt2[bh][nblk=n>>4][ks=k>>5][l*8]   : chunk holds n nblk*16+r, k ks*32+quad*8..+8
// Every attn fragment load = one contiguous 1KB wave transaction.

// ---------------------------------------------------------------------------
// Kernel 1 (prep): 160 blocks.
//   blocks 0..127: Fb[which][n=h*32+f][e] = sum_d W[h*64+d][e]*freqs[h][d][f]
//   blocks 128..143: Wo fp32 -> bf16;  144..159: Wv fp32 -> bf16
// ---------------------------------------------------------------------------
__global__ __launch_bounds__(256) void prep(const float* __restrict__ Wq,
                                            const float* __restrict__ Wk,
                                            const float* __restrict__ freqs,
                                            const float* __restrict__ Wo,
                                            const float* __restrict__ Wv,
                                            bf16* __restrict__ Fqb,
                                            bf16* __restrict__ Fkb,
                                            bf16* __restrict__ Wo_bf,
                                            bf16* __restrict__ Wv_bf) {
    int bx = blockIdx.x, t = threadIdx.x;
    if (bx < 128) {
        int which = bx >> 6, h = (bx >> 3) & 7, ec = bx & 7;
        const float* W = which ? Wk : Wq;
        bf16* Fb = which ? Fkb : Fqb;
        int f = t & 31, el = t >> 5;
        int e = ec * 8 + el;
        float acc = 0.f;
        for (int d = 0; d < 64; ++d)
            acc += W[(h * 64 + d) * 64 + e] * freqs[(h * 64 + d) * 32 + f];
        Fb[(h * 32 + f) * 64 + e] = __float2bfloat16(acc);
    } else {
        const float* src = (bx < 144) ? Wo : Wv;
        bf16* dst = (bx < 144) ? Wo_bf : Wv_bf;
        int gid = ((bx - 128) & 15) * 256 + t;
        #pragma unroll
        for (int i = 0; i < 2; ++i) {
            int idx4 = gid * 2 + i;
            float4 v = ((const float4*)src)[idx4];
            union { bf16 ob[4]; uint2 u; } pk;
            pk.ob[0] = __float2bfloat16(v.x); pk.ob[1] = __float2bfloat16(v.y);
            pk.ob[2] = __float2bfloat16(v.z); pk.ob[3] = __float2bfloat16(v.w);
            *(uint2*)(dst + idx4 * 4) = pk.u;
        }
    }
}

// ---------------------------------------------------------------------------
// Kernel 2 (fat, MFMA): blocks 0..1023 = encode; 1024..2047 = vproj.
// ---------------------------------------------------------------------------
__global__ __launch_bounds__(256) void encvp(const float* __restrict__ qa_in,
                                             const float* __restrict__ ql,
                                             const float* __restrict__ ka_in,
                                             const float* __restrict__ kl,
                                             const bf16* __restrict__ Fqb,
                                             const bf16* __restrict__ Fkb,
                                             bf16* __restrict__ qf,
                                             bf16* __restrict__ kf,
                                             const float* __restrict__ va_in,
                                             const bf16* __restrict__ Wv_bf,
                                             bf16* __restrict__ Vt) {
    __shared__ __align__(16) bf16 smem[20480];   // 40KB, unioned per path
    int t = threadIdx.x;
    int w = t >> 6, l = t & 63;
    int quad = l >> 4, r = l & 15;

    if (blockIdx.x < 1024) {
        // ================= encode path =================
        int blk = blockIdx.x;
        int xbase = blk * 4;             // 4 (b,s) groups
        int b = xbase >> 10, s0 = xbase & 1023;
        float* wgtF = (float*)smem;              // [2][32] floats
        bf16* zL = smem + 256;                   // 4096 shorts
        int tw = w & 1, nb = (w >> 1) * 8;

        if (t < 64) {
            int which = t >> 5, row = t & 31;
            int si = row >> 3, m = row & 7;
            const float* lwp = (which ? kl : ql) + (size_t)(xbase + si) * 8;
            float lw[8]; float mx = -1e30f;
            #pragma unroll
            for (int j = 0; j < 8; ++j) { lw[j] = lwp[j]; mx = fmaxf(mx, lw[j]); }
            float sm = 0.f;
            #pragma unroll
            for (int j = 0; j < 8; ++j) sm += __expf(lw[j] - mx);
            const float rs = 0.17677669529663687f;  // 1/sqrt(32)
            float osc = which ? rs : rs * 0.125f;
            wgtF[which * 32 + row] = __expf(lw[m] - mx) * (osc / sm);
        }
        __syncthreads();

        for (int which = 0; which < 2; ++which) {
            const float* at = which ? ka_in : qa_in;
            const bf16* Fb = which ? Fkb : Fqb;

            const float* arow = at + ((size_t)(blk * 32 + tw * 16 + r)) * 64 + quad * 8;
            float4 af0 = *(const float4*)(arow);
            float4 af1 = *(const float4*)(arow + 4);
            float4 af2 = *(const float4*)(arow + 32);
            float4 af3 = *(const float4*)(arow + 36);
            short8 a0 = pack8(af0, af1);
            short8 a1 = pack8(af2, af3);

            floatx4 acc[8];
            #pragma unroll
            for (int nt = 0; nt < 8; ++nt) {
                int n = (nb + nt) * 16 + r;
                short8 b0 = *(const short8*)(Fb + n * 64 + quad * 8);
                short8 b1 = *(const short8*)(Fb + n * 64 + quad * 8 + 32);
                floatx4 c = {0.f, 0.f, 0.f, 0.f};
                c = mfma16(a0, b0, c);
                c = mfma16(a1, b1, c);
                acc[nt] = c;
            }

            float wv[4];
            #pragma unroll
            for (int reg = 0; reg < 4; ++reg)
                wv[reg] = wgtF[which * 32 + tw * 16 + quad * 4 + reg];

            int si = tw * 2 + (quad >> 1);
            int iss = quad & 1;
            #pragma unroll
            for (int nt = 0; nt < 8; ++nt) {
                int n = (nb + nt) * 16 + r;
                int h = n >> 5, f = n & 31;
                float zc = 0.f, zs = 0.f;
                #pragma unroll
                for (int reg = 0; reg < 4; ++reg) {
                    float sv, cv;
                    __sincosf(acc[nt][reg], &sv, &cv);
                    zc += wv[reg] * cv;
                    zs += wv[reg] * sv;
                }
                zc += __shfl_xor(zc, 16);
                zs += __shfl_xor(zs, 16);
                float val = iss ? zs : zc;
                zL[((which * 4 + si) * 8 + h) * 64 + f + 32 * iss] = __float2bfloat16(val);
            }
        }
        __syncthreads();

        // output in fragment-order layout
        #pragma unroll
        for (int rep = 0; rep < 2; ++rep) {
            int idx = rep * 256 + t;
            int row = idx >> 3, c = idx & 7;     // row = which*32+si*8+h, c = f-chunk
            int which = row >> 5, si = (row >> 3) & 3, h = row & 7;
            bf16* enc = which ? kf : qf;
            short8 v = *(const short8*)(zL + row * 64 + c * 8);
            int s = s0 + si;
            int bh = b * 8 + h;
            int kt = s >> 4, half = c >> 2, qd = c & 3;
            *(short8*)(enc + ((size_t)((bh * 64 + kt) * 2 + half)) * 512
                           + (qd * 16 + (s & 15)) * 8) = v;
        }
    } else {
        // ================= vproj path =================
        int vp = blockIdx.x - 1024;
        int bh = vp & 31, sc = vp >> 5;
        int b = bh >> 3, h = bh & 7;
        bf16* atb = smem;
        bf16* os = smem;

        const float* src = va_in + ((size_t)(b * 1024 + sc * 32)) * 512;
        #pragma unroll
        for (int j = 0; j < 16; ++j) {
            int idx4 = j * 256 + t;
            float4 v = ((const float4*)src)[idx4];
            int flat = idx4 * 4;
            int s = flat >> 9, m = (flat >> 6) & 7, e = flat & 63;
            union { bf16 ob[4]; uint2 u; } pk;
            pk.ob[0] = __float2bfloat16(v.x); pk.ob[1] = __float2bfloat16(v.y);
            pk.ob[2] = __float2bfloat16(v.z); pk.ob[3] = __float2bfloat16(v.w);
            *(uint2*)(atb + (m * 32 + s) * AT_STRIDE + e) = pk.u;
        }
        __syncthreads();

        int dhalf = w & 1, sg = w >> 1;
        short8 aw0[2], aw1[2];
        #pragma unroll
        for (int dt = 0; dt < 2; ++dt) {
            int d = dhalf * 32 + dt * 16 + r;
            aw0[dt] = *(const short8*)(Wv_bf + (h * 64 + d) * 64 + quad * 8);
            aw1[dt] = *(const short8*)(Wv_bf + (h * 64 + d) * 64 + quad * 8 + 32);
        }
        floatx4 acc[8][2];
        #pragma unroll
        for (int m = 0; m < 8; ++m)
            #pragma unroll
            for (int dt = 0; dt < 2; ++dt) acc[m][dt] = (floatx4){0.f, 0.f, 0.f, 0.f};

        #pragma unroll
        for (int m = 0; m < 8; ++m) {
            short8 b0 = *(const short8*)(atb + (m * 32 + sg * 16 + r) * AT_STRIDE + quad * 8);
            short8 b1 = *(const short8*)(atb + (m * 32 + sg * 16 + r) * AT_STRIDE + quad * 8 + 32);
            #pragma unroll
            for (int dt = 0; dt < 2; ++dt) {
                acc[m][dt] = mfma16(aw0[dt], b0, acc[m][dt]);
                acc[m][dt] = mfma16(aw1[dt], b1, acc[m][dt]);
            }
        }
        __syncthreads();

        #pragma unroll
        for (int m = 0; m < 8; ++m)
            #pragma unroll
            for (int dt = 0; dt < 2; ++dt)
                #pragma unroll
                for (int reg = 0; reg < 4; ++reg) {
                    int n = m * 64 + dhalf * 32 + dt * 16 + quad * 4 + reg;
                    os[n * VO_STRIDE + sg * 16 + r] = __float2bfloat16(acc[m][dt][reg]);
                }
        __syncthreads();

        // fragment-order store: chunk (nblk, lane lv) <- os[nblk*16+rv][qv*8..]
        #pragma unroll
        for (int j = 0; j < 8; ++j) {
            int ch = j * 256 + t;              // 2048 chunks of 8 shorts
            int nblk = ch >> 6, lv = ch & 63;
            int rv = lv & 15, qv = lv >> 4;
            short8 v = *(const short8*)(os + (nblk * 16 + rv) * VO_STRIDE + qv * 8);
            *(short8*)(Vt + ((size_t)(bh * 32 + nblk) * 32 + sc) * 512 + lv * 8) = v;
        }
    }
}

// ---------------------------------------------------------------------------
// Kernel 3: attention via MFMA.  1024 blocks (XCD-affine), 512 thr = 8 waves.
// All global fragment loads are contiguous 1KB wave transactions (fragment-
// order layouts).  Sc[32][1024] bf16 = 64KB LDS, XOR-swizzled 16B chunks.
// ---------------------------------------------------------------------------
__global__ __launch_bounds__(512, 4) void attn_kern(const bf16* __restrict__ qf,
                                                    const bf16* __restrict__ kf,
                                                    const bf16* __restrict__ Vt,
                                                    bf16* __restrict__ tmp) {
    int n = blockIdx.x;
    int bh = (n & 7) + 8 * (n >> 8);
    int qb = (n >> 3) & 31;
    int b = bh >> 3, h = bh & 7;

    __shared__ __align__(16) bf16 Sc[32 * 1024];   // 64KB
    int t = threadIdx.x;
    int w = t >> 6, l = t & 63;         // w in [0,8)
    int quad = l >> 4, r = l & 15;
    int k7 = r & 7;

    // ---- Phase 1: QK^T transposed (A=K-tile, B=Q-tiles -> D[k][q]).
    const bf16* qfb = qf + (size_t)(bh * 128 + qb * 4) * 512 + l * 8;
    short8 q0 = *(const short8*)(qfb);
    short8 q1 = *(const short8*)(qfb + 512);
    short8 q2 = *(const short8*)(qfb + 1024);
    short8 q3 = *(const short8*)(qfb + 1536);

    // wave w: k-tiles w*8 .. w*8+7; distance-2 prefetch; 2KB per k-tile
    const bf16* kfb = kf + (size_t)(bh * 128) * 512 + l * 8;
    short8 kA0 = *(const short8*)(kfb + (size_t)(w * 8) * 1024);
    short8 kA1 = *(const short8*)(kfb + (size_t)(w * 8) * 1024 + 512);
    short8 kB0 = *(const short8*)(kfb + (size_t)(w * 8 + 1) * 1024);
    short8 kB1 = *(const short8*)(kfb + (size_t)(w * 8 + 1) * 1024 + 512);

    #pragma unroll
    for (int i = 0; i < 8; ++i) {
        short8 k0 = kA0, k1 = kA1;
        kA0 = kB0; kA1 = kB1;
        if (i < 6) {
            kB0 = *(const short8*)(kfb + (size_t)(w * 8 + i + 2) * 1024);
            kB1 = *(const short8*)(kfb + (size_t)(w * 8 + i + 2) * 1024 + 512);
        }
        floatx4 c0 = {0.f, 0.f, 0.f, 0.f}, c1 = {0.f, 0.f, 0.f, 0.f};
        c0 = mfma16(k0, q0, c0); c0 = mfma16(k1, q1, c0);
        c1 = mfma16(k0, q2, c1); c1 = mfma16(k1, q3, c1);
        int ktl = w * 8 + i;
        int chunk = ktl * 2 + (quad >> 1);
        int sw = ((chunk ^ k7) << 3) + (quad & 1) * 4;
        union { uint2 u; bf16 bb[4]; } p0, p1;
        #pragma unroll
        for (int reg = 0; reg < 4; ++reg) {
            p0.bb[reg] = __float2bfloat16(c0[reg]);
            p1.bb[reg] = __float2bfloat16(c1[reg]);
        }
        *(uint2*)(Sc + r * 1024 + sw) = p0.u;
        *(uint2*)(Sc + (r + 16) * 1024 + sw) = p1.u;
    }
    __syncthreads();

    // ---- Phase 2: softmax, normalized in place (wave w: rows w*4..w*4+3)
    for (int i = 0; i < 4; ++i) {
        int row = w * 4 + i;
        int key = row & 7;
        bf16* rowp = Sc + row * 1024;
        int p0 = ((2 * l) ^ key) << 3;
        int p1 = ((2 * l + 1) ^ key) << 3;
        union { short8 s; unsigned short u[8]; } v0, v1;
        v0.s = *(const short8*)(rowp + p0);
        v1.s = *(const short8*)(rowp + p1);
        float f[16];
        #pragma unroll
        for (int j = 0; j < 8; ++j) { f[j] = us2f(v0.u[j]); f[8 + j] = us2f(v1.u[j]); }
        float mx = -1e30f;
        #pragma unroll
        for (int j = 0; j < 16; ++j) mx = fmaxf(mx, f[j]);
        #pragma unroll
        for (int off = 32; off; off >>= 1) mx = fmaxf(mx, __shfl_xor(mx, off));
        float sm = 0.f;
        #pragma unroll
        for (int j = 0; j < 16; ++j) { f[j] = __expf(f[j] - mx); sm += f[j]; }
        #pragma unroll
        for (int off = 32; off; off >>= 1) sm += __shfl_xor(sm, off);
        float inv = 1.f / sm;
        #pragma unroll
        for (int j = 0; j < 8; ++j) {
            v0.u[j] = (unsigned short)(__bfloat16_as_ushort(__float2bfloat16(f[j] * inv)));
            v1.u[j] = (unsigned short)(__bfloat16_as_ushort(__float2bfloat16(f[8 + j] * inv)));
        }
        *(short8*)(rowp + p0) = v0.s;
        *(short8*)(rowp + p1) = v1.s;
    }
    __syncthreads();

    // ---- Phase 3: P@V.  wave w: nblk w*4..w*4+3, both 16-row tiles.
    // Distance-2 prefetch; all loads contiguous 1KB.
    floatx4 acc0[4], acc1[4];
    #pragma unroll
    for (int nt = 0; nt < 4; ++nt) {
        acc0[nt] = (floatx4){0.f, 0.f, 0.f, 0.f};
        acc1[nt] = (floatx4){0.f, 0.f, 0.f, 0.f};
    }
    const bf16* vbase = Vt + ((size_t)(bh * 32 + w * 4) * 32) * 512 + l * 8;
    short8 vA[4], vB[4], vC[4];
    #pragma unroll
    for (int nt = 0; nt < 4; ++nt) vA[nt] = *(const short8*)(vbase + nt * 16384);
    #pragma unroll
    for (int nt = 0; nt < 4; ++nt) vB[nt] = *(const short8*)(vbase + nt * 16384 + 512);

    #pragma unroll
    for (int ks = 0; ks < 32; ++ks) {
        if (ks < 30) {
            #pragma unroll
            for (int nt = 0; nt < 4; ++nt)
                vC[nt] = *(const short8*)(vbase + nt * 16384 + (ks + 2) * 512);
        }
        int pc = (((ks * 4 + quad) ^ k7) << 3);
        short8 pa0 = *(const short8*)(Sc + r * 1024 + pc);
        short8 pa1 = *(const short8*)(Sc + (16 + r) * 1024 + pc);
        #pragma unroll
        for (int nt = 0; nt < 4; ++nt) {
            acc0[nt] = mfma16(pa0, vA[nt], acc0[nt]);
            acc1[nt] = mfma16(pa1, vA[nt], acc1[nt]);
        }
        #pragma unroll
        for (int nt = 0; nt < 4; ++nt) { vA[nt] = vB[nt]; vB[nt] = vC[nt]; }
    }
    __syncthreads();   // all Sc reads done; reuse for output staging

    bf16* Ob = Sc;
    #pragma unroll
    for (int nt = 0; nt < 4; ++nt)
        #pragma unroll
        for (int reg = 0; reg < 4; ++reg) {
            int col = w * 64 + nt * 16 + r;
            Ob[(quad * 4 + reg) * OB_STRIDE + col] = __float2bfloat16(acc0[nt][reg]);
            Ob[(quad * 4 + reg + 16) * OB_STRIDE + col] = __float2bfloat16(acc1[nt][reg]);
        }
    __syncthreads();

    // coalesced store: 32 rows x 512 cols bf16 -> tmp[b][q][m][h][d]
    #pragma unroll
    for (int i = 0; i < 4; ++i) {
        int c = i * 512 + t;          // 0..2047 chunks of 8 bf16
        int row = c >> 6, j = c & 63;
        int m = j >> 3, d0 = (j & 7) * 8;
        short8 v = *(const short8*)(Ob + row * OB_STRIDE + j * 8);
        *(short8*)(tmp + ((((size_t)(b * 1024 + qb * 32 + row) * 8 + m) * 8 + h) * 64 + d0)) = v;
    }
}

// ---------------------------------------------------------------------------
// Kernel 4 (MFMA): out_atoms[row, o] = tmp[row, :512] @ Wo_bf[o, :512]
// ---------------------------------------------------------------------------
__global__ __launch_bounds__(256) void finalize(const bf16* __restrict__ tmp,
                                                const bf16* __restrict__ Wo_bf,
                                                const float* __restrict__ Ww,
                                                const float* __restrict__ ql,
                                                float* __restrict__ out) {
    __shared__ __align__(16) float Os[64][OS_STRIDE];   // 17.4 KB
    __shared__ float fs[8][64];
    int t = threadIdx.x;
    int w = t >> 6, l = t & 63;
    int quad = l >> 4, r = l & 15;
    size_t rowbase = (size_t)blockIdx.x * 64;

    floatx4 acc[4];
    #pragma unroll
    for (int nt = 0; nt < 4; ++nt) acc[nt] = (floatx4){0.f, 0.f, 0.f, 0.f};

    const bf16* arow = tmp + (rowbase + w * 16 + r) * 512 + quad * 8;
    const bf16* brow = Wo_bf + r * 512 + quad * 8;

    for (int ks = 0; ks < 16; ++ks) {
        short8 a = *(const short8*)(arow + ks * 32);
        #pragma unroll
        for (int nt = 0; nt < 4; ++nt) {
            short8 bb = *(const short8*)(brow + nt * 16 * 512 + ks * 32);
            acc[nt] = mfma16(a, bb, acc[nt]);
        }
    }
    #pragma unroll
    for (int nt = 0; nt < 4; ++nt)
        #pragma unroll
        for (int reg = 0; reg < 4; ++reg)
            Os[w * 16 + quad * 4 + reg][nt * 16 + r] = acc[nt][reg];
    __syncthreads();

    #pragma unroll
    for (int i = 0; i < 4; ++i) {
        int ch = i * 256 + t;
        int rr = ch >> 4, c4 = (ch & 15) * 4;
        float4 v = *(const float4*)&Os[rr][c4];
        *(float4*)(out + (rowbase + rr) * 64 + c4) = v;
    }

    {
        int g = t >> 5, oo = (t & 31) * 2;
        float f0 = 0.f, f1 = 0.f;
        #pragma unroll
        for (int m = 0; m < 8; ++m) {
            f0 += Os[g * 8 + m][oo];
            f1 += Os[g * 8 + m][oo + 1];
        }
        fs[g][oo] = f0 * 0.125f;
        fs[g][oo + 1] = f1 * 0.125f;
    }
    __syncthreads();

    if (t < 64) {
        int g = t >> 3, mm = t & 7;
        size_t x = (size_t)blockIdx.x * 8 + g;
        float nl = ql[x * 8 + mm];
        #pragma unroll
        for (int o = 0; o < 64; ++o) nl += fs[g][o] * Ww[mm * 64 + o];
        out[(size_t)CB * CS * CM * CD + x * 8 + mm] = nl;
    }
}

// ---------------------------------------------------------------------------
extern "C" void kernel_launch(void* const* d_in, const int* in_sizes, int n_in,
                              void* d_out, int out_size, void* d_ws, size_t ws_size,
                              hipStream_t stream) {
    const float* q_atoms = (const float*)d_in[0];
    const float* q_logw  = (const float*)d_in[1];
    const float* k_atoms = (const float*)d_in[2];
    const float* k_logw  = (const float*)d_in[3];
    const float* v_atoms = (const float*)d_in[4];
    // d_in[5] = v_logw (unused by the reference)
    const float* Wq = (const float*)d_in[6];
    const float* Wk = (const float*)d_in[7];
    const float* Wv = (const float*)d_in[8];
    const float* Wo = (const float*)d_in[9];
    const float* Ww = (const float*)d_in[10];
    const float* freqs = (const float*)d_in[11];

    // ws layout (all bf16): Fqb[16384] | Fkb[16384] | qf[2097152]
    //   | kf[2097152] | Vt[16777216] | tmp[16777216] | Wo_bf[32768] | Wv_bf[32768]
    bf16* Fqb = (bf16*)d_ws;
    bf16* Fkb = Fqb + 16384;
    bf16* qf = Fkb + 16384;
    bf16* kf = qf + 2097152;
    bf16* Vt = kf + 2097152;
    bf16* tmp = Vt + 16777216;
    bf16* Wo_bf = tmp + 16777216;
    bf16* Wv_bf = Wo_bf + 32768;
    float* out = (float*)d_out;

    prep<<<160, 256, 0, stream>>>(Wq, Wk, freqs, Wo, Wv, Fqb, Fkb, Wo_bf, Wv_bf);
    encvp<<<2048, 256, 0, stream>>>(q_atoms, q_logw, k_atoms, k_logw,
                                    Fqb, Fkb, qf, kf,
                                    v_atoms, Wv_bf, Vt);
    attn_kern<<<1024, 512, 0, stream>>>(qf, kf, Vt, tmp);
    finalize<<<CB * CS / 8, 256, 0, stream>>>(tmp, Wo_bf, Ww, q_logw, out);
}

// Round 13
// 184.672 us; speedup vs baseline: 2.4376x; 1.0996x over previous
//
#include <hip/hip_runtime.h>
#include <hip/hip_bf16.h>

typedef __hip_bfloat16 bf16;
typedef __attribute__((ext_vector_type(8))) short short8;
typedef __attribute__((ext_vector_type(4))) float floatx4;

// Problem constants: B=4, S=1024, M=8, D=64, H=8, NF=32, HD=512
#define CB 4
#define CS 1024
#define CM 8
#define CD 64
#define CH 8
#define CNF 32
#define CHD 512

#define OB_STRIDE 520    // attn epilogue staging stride (bf16)
#define OS_STRIDE 68     // finalize staging stride (fp32)
#define AT_STRIDE 72     // LDS atom-row stride (shorts): 36 words -> bank spread
#define VO_STRIDE 40     // vproj output staging stride (shorts)

__device__ __forceinline__ float b2f(bf16 x) { return __bfloat162float(x); }
__device__ __forceinline__ float us2f(unsigned short u) {
    union { unsigned int i; float f; } v; v.i = ((unsigned int)u) << 16; return v.f;
}
__device__ __forceinline__ floatx4 mfma16(short8 a, short8 b, floatx4 c) {
    return __builtin_amdgcn_mfma_f32_16x16x32_bf16(a, b, c, 0, 0, 0);
}

// Fragment-order layouts: a "chunk" is 512 bf16 = 1KB = one wave transaction;
// chunk lane l = quad*16 + r holds 8 contiguous elements.
//   Fbf  [ntile(n>>4)][half(e>>5)]        : row n=ntile*16+r, e=half*32+quad*8+j
//   qf/kf[bh][kt(s>>4)][half(f>>5)]       : row s=kt*16+r,   f=half*32+quad*8+j
//   Vt   [bh][nblk(n>>4)][ks(k>>5)]       : row n=nblk*16+r, k=ks*32+quad*8+j
//   Wvf  [h][dt4(d>>4)][ehalf(e>>5)]      : row d=dt4*16+r,  e=ehalf*32+quad*8+j
//   Wof  [ot(o>>4)][ks(k>>5)]             : row o=ot*16+r,   k=ks*32+quad*8+j
//   tmpf [tile(g>>4)][ks(k>>5)]           : row g=tile*16+r, k=ks*32+quad*8+j
//        (g = (b*1024+q)*8+m, k = h*64+d; row-in-tile = 8*(q&1)+m)

// ---------------------------------------------------------------------------
// Kernel 1 (prep): 160 blocks.  All outputs in fragment-order.
// ---------------------------------------------------------------------------
__global__ __launch_bounds__(256) void prep(const float* __restrict__ Wq,
                                            const float* __restrict__ Wk,
                                            const float* __restrict__ freqs,
                                            const float* __restrict__ Wo,
                                            const float* __restrict__ Wv,
                                            bf16* __restrict__ Fqb,
                                            bf16* __restrict__ Fkb,
                                            bf16* __restrict__ Wof,
                                            bf16* __restrict__ Wvf) {
    int bx = blockIdx.x, t = threadIdx.x;
    if (bx < 128) {
        int which = bx >> 6, h = (bx >> 3) & 7, ec = bx & 7;
        const float* W = which ? Wk : Wq;
        bf16* Fb = which ? Fkb : Fqb;
        int f = t & 31, el = t >> 5;
        int e = ec * 8 + el;
        float acc = 0.f;
        for (int d = 0; d < 64; ++d)
            acc += W[(h * 64 + d) * 64 + e] * freqs[(h * 64 + d) * 32 + f];
        int ntile = h * 2 + (f >> 4);
        int half = e >> 5, quad = (e >> 3) & 3, j = e & 7;
        Fb[(ntile * 2 + half) * 512 + quad * 128 + (f & 15) * 8 + j] = __float2bfloat16(acc);
    } else if (bx < 144) {
        int gid = (bx - 128) * 256 + t;
        #pragma unroll
        for (int i = 0; i < 2; ++i) {
            int idx4 = gid * 2 + i;
            float4 v = ((const float4*)Wo)[idx4];
            int flat = idx4 * 4;
            int o = flat >> 9, k0 = flat & 511;
            int ot = o >> 4, r0 = o & 15;
            int ks = k0 >> 5, qd = (k0 >> 3) & 3, j0 = k0 & 7;
            union { bf16 ob[4]; uint2 u; } pk;
            pk.ob[0] = __float2bfloat16(v.x); pk.ob[1] = __float2bfloat16(v.y);
            pk.ob[2] = __float2bfloat16(v.z); pk.ob[3] = __float2bfloat16(v.w);
            *(uint2*)(Wof + (ot * 16 + ks) * 512 + qd * 128 + r0 * 8 + j0) = pk.u;
        }
    } else {
        int gid = (bx - 144) * 256 + t;
        #pragma unroll
        for (int i = 0; i < 2; ++i) {
            int idx4 = gid * 2 + i;
            float4 v = ((const float4*)Wv)[idx4];
            int flat = idx4 * 4;
            int c = flat >> 6, e0 = flat & 63;
            int h2 = c >> 6, d = c & 63;
            int ehalf = e0 >> 5, qd = (e0 >> 3) & 3, j0 = e0 & 7;
            union { bf16 ob[4]; uint2 u; } pk;
            pk.ob[0] = __float2bfloat16(v.x); pk.ob[1] = __float2bfloat16(v.y);
            pk.ob[2] = __float2bfloat16(v.z); pk.ob[3] = __float2bfloat16(v.w);
            *(uint2*)(Wvf + (h2 * 8 + (d >> 4) * 2 + ehalf) * 512
                          + qd * 128 + (d & 15) * 8 + j0) = pk.u;
        }
    }
}

// ---------------------------------------------------------------------------
// Kernel 2 (fat, MFMA): blocks 0..1023 = encode; 1024..2047 = vproj.
// All global fragment loads contiguous 1KB; atoms staged via LDS.
// ---------------------------------------------------------------------------
__global__ __launch_bounds__(256) void encvp(const float* __restrict__ qa_in,
                                             const float* __restrict__ ql,
                                             const float* __restrict__ ka_in,
                                             const float* __restrict__ kl,
                                             const bf16* __restrict__ Fqb,
                                             const bf16* __restrict__ Fkb,
                                             bf16* __restrict__ qf,
                                             bf16* __restrict__ kf,
                                             const float* __restrict__ va_in,
                                             const bf16* __restrict__ Wvf,
                                             bf16* __restrict__ Vt) {
    __shared__ __align__(16) bf16 smem[20480];   // 40KB, unioned per path
    int t = threadIdx.x;
    int w = t >> 6, l = t & 63;
    int quad = l >> 4, r = l & 15;

    if (blockIdx.x < 1024) {
        // ================= encode path =================
        int blk = blockIdx.x;
        int xbase = blk * 4;             // 4 (b,s) groups
        int b = xbase >> 10, s0 = xbase & 1023;
        float* wgtF = (float*)smem;              // 64 floats = 128 shorts
        bf16* atq = smem + 128;                  // 32*72 = 2304
        bf16* atk = smem + 128 + 2304;           // 2304
        bf16* zL  = smem + 128 + 4608;           // 4096
        int tw = w & 1, nb = (w >> 1) * 8;

        // stage atoms q & k: 32 rows x 64 fp32 each = 512 float4 per input
        {
            const float* srcq = qa_in + (size_t)(blk * 32) * 64;
            const float* srck = ka_in + (size_t)(blk * 32) * 64;
            #pragma unroll
            for (int j = 0; j < 2; ++j) {        // FIX: 512 float4 / 256 thr = 2
                int idx4 = j * 256 + t;
                int flat = idx4 * 4;
                int row = flat >> 6, e = flat & 63;
                float4 vq = ((const float4*)srcq)[idx4];
                float4 vk = ((const float4*)srck)[idx4];
                union { bf16 ob[4]; uint2 u; } pq, pk2;
                pq.ob[0] = __float2bfloat16(vq.x); pq.ob[1] = __float2bfloat16(vq.y);
                pq.ob[2] = __float2bfloat16(vq.z); pq.ob[3] = __float2bfloat16(vq.w);
                pk2.ob[0] = __float2bfloat16(vk.x); pk2.ob[1] = __float2bfloat16(vk.y);
                pk2.ob[2] = __float2bfloat16(vk.z); pk2.ob[3] = __float2bfloat16(vk.w);
                *(uint2*)(atq + row * AT_STRIDE + e) = pq.u;
                *(uint2*)(atk + row * AT_STRIDE + e) = pk2.u;
            }
        }
        if (t < 64) {
            int which = t >> 5, row = t & 31;
            int si = row >> 3, m = row & 7;
            const float* lwp = (which ? kl : ql) + (size_t)(xbase + si) * 8;
            float lw[8]; float mx = -1e30f;
            #pragma unroll
            for (int j = 0; j < 8; ++j) { lw[j] = lwp[j]; mx = fmaxf(mx, lw[j]); }
            float sm = 0.f;
            #pragma unroll
            for (int j = 0; j < 8; ++j) sm += __expf(lw[j] - mx);
            const float rs = 0.17677669529663687f;  // 1/sqrt(32)
            float osc = which ? rs : rs * 0.125f;
            wgtF[which * 32 + row] = __expf(lw[m] - mx) * (osc / sm);
        }
        __syncthreads();

        for (int which = 0; which < 2; ++which) {
            const bf16* atb2 = which ? atk : atq;
            const bf16* Fb = which ? Fkb : Fqb;

            short8 a0 = *(const short8*)(atb2 + (tw * 16 + r) * AT_STRIDE + quad * 8);
            short8 a1 = *(const short8*)(atb2 + (tw * 16 + r) * AT_STRIDE + quad * 8 + 32);

            floatx4 acc[8];
            #pragma unroll
            for (int nt = 0; nt < 8; ++nt) {
                int ntile = nb + nt;
                short8 b0 = *(const short8*)(Fb + (ntile * 2 + 0) * 512 + l * 8);
                short8 b1 = *(const short8*)(Fb + (ntile * 2 + 1) * 512 + l * 8);
                floatx4 c = {0.f, 0.f, 0.f, 0.f};
                c = mfma16(a0, b0, c);
                c = mfma16(a1, b1, c);
                acc[nt] = c;
            }

            float wv[4];
            #pragma unroll
            for (int reg = 0; reg < 4; ++reg)
                wv[reg] = wgtF[which * 32 + tw * 16 + quad * 4 + reg];

            int si = tw * 2 + (quad >> 1);
            int iss = quad & 1;
            #pragma unroll
            for (int nt = 0; nt < 8; ++nt) {
                int n = (nb + nt) * 16 + r;
                int h = n >> 5, f = n & 31;
                float zc = 0.f, zs = 0.f;
                #pragma unroll
                for (int reg = 0; reg < 4; ++reg) {
                    float sv, cv;
                    __sincosf(acc[nt][reg], &sv, &cv);
                    zc += wv[reg] * cv;
                    zs += wv[reg] * sv;
                }
                zc += __shfl_xor(zc, 16);
                zs += __shfl_xor(zs, 16);
                float val = iss ? zs : zc;
                zL[((which * 4 + si) * 8 + h) * 64 + f + 32 * iss] = __float2bfloat16(val);
            }
        }
        __syncthreads();

        // output in fragment-order layout
        #pragma unroll
        for (int rep = 0; rep < 2; ++rep) {
            int idx = rep * 256 + t;
            int row = idx >> 3, c = idx & 7;     // row = which*32+si*8+h, c = f-chunk
            int which = row >> 5, si = (row >> 3) & 3, h = row & 7;
            bf16* enc = which ? kf : qf;
            short8 v = *(const short8*)(zL + row * 64 + c * 8);
            int s = s0 + si;
            int bh = b * 8 + h;
            int kt = s >> 4, half = c >> 2, qd = c & 3;
            *(short8*)(enc + ((size_t)((bh * 64 + kt) * 2 + half)) * 512
                           + (qd * 16 + (s & 15)) * 8) = v;
        }
    } else {
        // ================= vproj path =================
        int vp = blockIdx.x - 1024;
        int bh = vp & 31, sc = vp >> 5;
        int b = bh >> 3, h = bh & 7;
        bf16* atb = smem;
        bf16* os = smem;

        const float* src = va_in + ((size_t)(b * 1024 + sc * 32)) * 512;
        #pragma unroll
        for (int j = 0; j < 16; ++j) {
            int idx4 = j * 256 + t;
            float4 v = ((const float4*)src)[idx4];
            int flat = idx4 * 4;
            int s = flat >> 9, m = (flat >> 6) & 7, e = flat & 63;
            union { bf16 ob[4]; uint2 u; } pk;
            pk.ob[0] = __float2bfloat16(v.x); pk.ob[1] = __float2bfloat16(v.y);
            pk.ob[2] = __float2bfloat16(v.z); pk.ob[3] = __float2bfloat16(v.w);
            *(uint2*)(atb + (m * 32 + s) * AT_STRIDE + e) = pk.u;
        }
        __syncthreads();

        int dhalf = w & 1, sg = w >> 1;
        short8 aw0[2], aw1[2];
        #pragma unroll
        for (int dt = 0; dt < 2; ++dt) {
            int dt4 = dhalf * 2 + dt;
            aw0[dt] = *(const short8*)(Wvf + (size_t)(h * 8 + dt4 * 2 + 0) * 512 + l * 8);
            aw1[dt] = *(const short8*)(Wvf + (size_t)(h * 8 + dt4 * 2 + 1) * 512 + l * 8);
        }
        floatx4 acc[8][2];
        #pragma unroll
        for (int m = 0; m < 8; ++m)
            #pragma unroll
            for (int dt = 0; dt < 2; ++dt) acc[m][dt] = (floatx4){0.f, 0.f, 0.f, 0.f};

        #pragma unroll
        for (int m = 0; m < 8; ++m) {
            short8 b0 = *(const short8*)(atb + (m * 32 + sg * 16 + r) * AT_STRIDE + quad * 8);
            short8 b1 = *(const short8*)(atb + (m * 32 + sg * 16 + r) * AT_STRIDE + quad * 8 + 32);
            #pragma unroll
            for (int dt = 0; dt < 2; ++dt) {
                acc[m][dt] = mfma16(aw0[dt], b0, acc[m][dt]);
                acc[m][dt] = mfma16(aw1[dt], b1, acc[m][dt]);
            }
        }
        __syncthreads();

        #pragma unroll
        for (int m = 0; m < 8; ++m)
            #pragma unroll
            for (int dt = 0; dt < 2; ++dt)
                #pragma unroll
                for (int reg = 0; reg < 4; ++reg) {
                    int n = m * 64 + dhalf * 32 + dt * 16 + quad * 4 + reg;
                    os[n * VO_STRIDE + sg * 16 + r] = __float2bfloat16(acc[m][dt][reg]);
                }
        __syncthreads();

        // fragment-order store: chunk (nblk, lane lv) <- os[nblk*16+rv][qv*8..]
        #pragma unroll
        for (int j = 0; j < 8; ++j) {
            int ch = j * 256 + t;              // 2048 chunks of 8 shorts
            int nblk = ch >> 6, lv = ch & 63;
            int rv = lv & 15, qv = lv >> 4;
            short8 v = *(const short8*)(os + (nblk * 16 + rv) * VO_STRIDE + qv * 8);
            *(short8*)(Vt + ((size_t)(bh * 32 + nblk) * 32 + sc) * 512 + lv * 8) = v;
        }
    }
}

// ---------------------------------------------------------------------------
// Kernel 3: attention via MFMA.  1024 blocks (XCD-affine), 512 thr = 8 waves.
// P1-P3 identical to round 11 (known-good 62us).  Epilogue stores tmpf in
// fragment-order for finalize (m-rotated LDS staging for bank spread).
// ---------------------------------------------------------------------------
__global__ __launch_bounds__(512, 4) void attn_kern(const bf16* __restrict__ qf,
                                                    const bf16* __restrict__ kf,
                                                    const bf16* __restrict__ Vt,
                                                    bf16* __restrict__ tmpf) {
    int n = blockIdx.x;
    int bh = (n & 7) + 8 * (n >> 8);
    int qb = (n >> 3) & 31;
    int b = bh >> 3, h = bh & 7;

    __shared__ __align__(16) bf16 Sc[32 * 1024];   // 64KB
    int t = threadIdx.x;
    int w = t >> 6, l = t & 63;         // w in [0,8)
    int quad = l >> 4, r = l & 15;
    int k7 = r & 7;

    // ---- Phase 1: QK^T transposed (A=K-tile, B=Q-tiles -> D[k][q]).
    const bf16* qfb = qf + (size_t)(bh * 128 + qb * 4) * 512 + l * 8;
    short8 q0 = *(const short8*)(qfb);
    short8 q1 = *(const short8*)(qfb + 512);
    short8 q2 = *(const short8*)(qfb + 1024);
    short8 q3 = *(const short8*)(qfb + 1536);

    const bf16* kfb = kf + (size_t)(bh * 128) * 512 + l * 8;
    short8 kA0 = *(const short8*)(kfb + (size_t)(w * 8) * 1024);
    short8 kA1 = *(const short8*)(kfb + (size_t)(w * 8) * 1024 + 512);
    short8 kB0 = *(const short8*)(kfb + (size_t)(w * 8 + 1) * 1024);
    short8 kB1 = *(const short8*)(kfb + (size_t)(w * 8 + 1) * 1024 + 512);

    #pragma unroll
    for (int i = 0; i < 8; ++i) {
        short8 k0 = kA0, k1 = kA1;
        kA0 = kB0; kA1 = kB1;
        if (i < 6) {
            kB0 = *(const short8*)(kfb + (size_t)(w * 8 + i + 2) * 1024);
            kB1 = *(const short8*)(kfb + (size_t)(w * 8 + i + 2) * 1024 + 512);
        }
        floatx4 c0 = {0.f, 0.f, 0.f, 0.f}, c1 = {0.f, 0.f, 0.f, 0.f};
        c0 = mfma16(k0, q0, c0); c0 = mfma16(k1, q1, c0);
        c1 = mfma16(k0, q2, c1); c1 = mfma16(k1, q3, c1);
        int ktl = w * 8 + i;
        int chunk = ktl * 2 + (quad >> 1);
        int sw = ((chunk ^ k7) << 3) + (quad & 1) * 4;
        union { uint2 u; bf16 bb[4]; } p0, p1;
        #pragma unroll
        for (int reg = 0; reg < 4; ++reg) {
            p0.bb[reg] = __float2bfloat16(c0[reg]);
            p1.bb[reg] = __float2bfloat16(c1[reg]);
        }
        *(uint2*)(Sc + r * 1024 + sw) = p0.u;
        *(uint2*)(Sc + (r + 16) * 1024 + sw) = p1.u;
    }
    __syncthreads();

    // ---- Phase 2: softmax, normalized in place (wave w: rows w*4..w*4+3)
    for (int i = 0; i < 4; ++i) {
        int row = w * 4 + i;
        int key = row & 7;
        bf16* rowp = Sc + row * 1024;
        int p0 = ((2 * l) ^ key) << 3;
        int p1 = ((2 * l + 1) ^ key) << 3;
        union { short8 s; unsigned short u[8]; } v0, v1;
        v0.s = *(const short8*)(rowp + p0);
        v1.s = *(const short8*)(rowp + p1);
        float f[16];
        #pragma unroll
        for (int j = 0; j < 8; ++j) { f[j] = us2f(v0.u[j]); f[8 + j] = us2f(v1.u[j]); }
        float mx = -1e30f;
        #pragma unroll
        for (int j = 0; j < 16; ++j) mx = fmaxf(mx, f[j]);
        #pragma unroll
        for (int off = 32; off; off >>= 1) mx = fmaxf(mx, __shfl_xor(mx, off));
        float sm = 0.f;
        #pragma unroll
        for (int j = 0; j < 16; ++j) { f[j] = __expf(f[j] - mx); sm += f[j]; }
        #pragma unroll
        for (int off = 32; off; off >>= 1) sm += __shfl_xor(sm, off);
        float inv = 1.f / sm;
        #pragma unroll
        for (int j = 0; j < 8; ++j) {
            v0.u[j] = (unsigned short)(__bfloat16_as_ushort(__float2bfloat16(f[j] * inv)));
            v1.u[j] = (unsigned short)(__bfloat16_as_ushort(__float2bfloat16(f[8 + j] * inv)));
        }
        *(short8*)(rowp + p0) = v0.s;
        *(short8*)(rowp + p1) = v1.s;
    }
    __syncthreads();

    // ---- Phase 3: P@V.  wave w: nblk w*4..w*4+3, both 16-row tiles.
    floatx4 acc0[4], acc1[4];
    #pragma unroll
    for (int nt = 0; nt < 4; ++nt) {
        acc0[nt] = (floatx4){0.f, 0.f, 0.f, 0.f};
        acc1[nt] = (floatx4){0.f, 0.f, 0.f, 0.f};
    }
    const bf16* vbase = Vt + ((size_t)(bh * 32 + w * 4) * 32) * 512 + l * 8;
    short8 vA[4], vB[4], vC[4];
    #pragma unroll
    for (int nt = 0; nt < 4; ++nt) vA[nt] = *(const short8*)(vbase + nt * 16384);
    #pragma unroll
    for (int nt = 0; nt < 4; ++nt) vB[nt] = *(const short8*)(vbase + nt * 16384 + 512);

    #pragma unroll
    for (int ks = 0; ks < 32; ++ks) {
        if (ks < 30) {
            #pragma unroll
            for (int nt = 0; nt < 4; ++nt)
                vC[nt] = *(const short8*)(vbase + nt * 16384 + (ks + 2) * 512);
        }
        int pc = (((ks * 4 + quad) ^ k7) << 3);
        short8 pa0 = *(const short8*)(Sc + r * 1024 + pc);
        short8 pa1 = *(const short8*)(Sc + (16 + r) * 1024 + pc);
        #pragma unroll
        for (int nt = 0; nt < 4; ++nt) {
            acc0[nt] = mfma16(pa0, vA[nt], acc0[nt]);
            acc1[nt] = mfma16(pa1, vA[nt], acc1[nt]);
        }
        #pragma unroll
        for (int nt = 0; nt < 4; ++nt) { vA[nt] = vB[nt]; vB[nt] = vC[nt]; }
    }
    __syncthreads();   // all Sc reads done; reuse for output staging

    // ---- Epilogue: stage with m-rotated columns, store tmpf fragment-order
    bf16* Ob = Sc;
    #pragma unroll
    for (int nt = 0; nt < 4; ++nt)
        #pragma unroll
        for (int reg = 0; reg < 4; ++reg) {
            int col = w * 64 + nt * 16 + r;
            int m = col >> 6, d = col & 63;
            int colS = m * 64 + ((d + m * 8) & 63);
            Ob[(quad * 4 + reg) * OB_STRIDE + colS] = __float2bfloat16(acc0[nt][reg]);
            Ob[(quad * 4 + reg + 16) * OB_STRIDE + colS] = __float2bfloat16(acc1[nt][reg]);
        }
    __syncthreads();

    // tmpf chunks: 16 T-tiles x 2 khalf; ks = h*2 + khalf
    #pragma unroll
    for (int i = 0; i < 4; ++i) {
        int ci = i * 8 + w;                 // 0..31
        int lv = t & 63;
        int T = ci >> 1, khalf = ci & 1;
        int quadv = lv >> 4, rv = lv & 15;
        int p = rv >> 3, m = rv & 7;
        int q_local = T * 2 + p;
        int d0 = khalf * 32 + quadv * 8;
        int colS = m * 64 + ((d0 + m * 8) & 63);
        short8 v = *(const short8*)(Ob + q_local * OB_STRIDE + colS);
        int GT = b * 512 + qb * 16 + T;
        *(short8*)(tmpf + ((size_t)(GT * 16 + h * 2 + khalf)) * 512 + lv * 8) = v;
    }
}

// ---------------------------------------------------------------------------
// Kernel 4 (MFMA): out_atoms[g, o] = tmpf-row g @ Wof row o.  All fragment
// loads contiguous 1KB.
// ---------------------------------------------------------------------------
__global__ __launch_bounds__(256) void finalize(const bf16* __restrict__ tmpf,
                                                const bf16* __restrict__ Wof,
                                                const float* __restrict__ Ww,
                                                const float* __restrict__ ql,
                                                float* __restrict__ out) {
    __shared__ __align__(16) float Os[64][OS_STRIDE];   // 17.4 KB
    __shared__ float fs[8][64];
    int t = threadIdx.x;
    int w = t >> 6, l = t & 63;
    int quad = l >> 4, r = l & 15;
    size_t rowbase = (size_t)blockIdx.x * 64;

    floatx4 acc[4];
    #pragma unroll
    for (int nt = 0; nt < 4; ++nt) acc[nt] = (floatx4){0.f, 0.f, 0.f, 0.f};

    const bf16* afrag = tmpf + ((size_t)(blockIdx.x * 4 + w) * 16) * 512 + l * 8;
    const bf16* bfrag = Wof + l * 8;

    for (int ks = 0; ks < 16; ++ks) {
        short8 a = *(const short8*)(afrag + ks * 512);
        #pragma unroll
        for (int nt = 0; nt < 4; ++nt) {
            short8 bb = *(const short8*)(bfrag + (size_t)(nt * 16 + ks) * 512);
            acc[nt] = mfma16(a, bb, acc[nt]);
        }
    }
    #pragma unroll
    for (int nt = 0; nt < 4; ++nt)
        #pragma unroll
        for (int reg = 0; reg < 4; ++reg)
            Os[w * 16 + quad * 4 + reg][nt * 16 + r] = acc[nt][reg];
    __syncthreads();

    #pragma unroll
    for (int i = 0; i < 4; ++i) {
        int ch = i * 256 + t;
        int rr = ch >> 4, c4 = (ch & 15) * 4;
        float4 v = *(const float4*)&Os[rr][c4];
        *(float4*)(out + (rowbase + rr) * 64 + c4) = v;
    }

    {
        int g = t >> 5, oo = (t & 31) * 2;
        float f0 = 0.f, f1 = 0.f;
        #pragma unroll
        for (int m = 0; m < 8; ++m) {
            f0 += Os[g * 8 + m][oo];
            f1 += Os[g * 8 + m][oo + 1];
        }
        fs[g][oo] = f0 * 0.125f;
        fs[g][oo + 1] = f1 * 0.125f;
    }
    __syncthreads();

    if (t < 64) {
        int g = t >> 3, mm = t & 7;
        size_t x = (size_t)blockIdx.x * 8 + g;
        float nl = ql[x * 8 + mm];
        #pragma unroll
        for (int o = 0; o < 64; ++o) nl += fs[g][o] * Ww[mm * 64 + o];
        out[(size_t)CB * CS * CM * CD + x * 8 + mm] = nl;
    }
}

// ---------------------------------------------------------------------------
extern "C" void kernel_launch(void* const* d_in, const int* in_sizes, int n_in,
                              void* d_out, int out_size, void* d_ws, size_t ws_size,
                              hipStream_t stream) {
    const float* q_atoms = (const float*)d_in[0];
    const float* q_logw  = (const float*)d_in[1];
    const float* k_atoms = (const float*)d_in[2];
    const float* k_logw  = (const float*)d_in[3];
    const float* v_atoms = (const float*)d_in[4];
    // d_in[5] = v_logw (unused by the reference)
    const float* Wq = (const float*)d_in[6];
    const float* Wk = (const float*)d_in[7];
    const float* Wv = (const float*)d_in[8];
    const float* Wo = (const float*)d_in[9];
    const float* Ww = (const float*)d_in[10];
    const float* freqs = (const float*)d_in[11];

    // ws layout (all bf16): Fqb[16384] | Fkb[16384] | qf[2097152]
    //   | kf[2097152] | Vt[16777216] | tmpf[16777216] | Wof[32768] | Wvf[32768]
    bf16* Fqb = (bf16*)d_ws;
    bf16* Fkb = Fqb + 16384;
    bf16* qf = Fkb + 16384;
    bf16* kf = qf + 2097152;
    bf16* Vt = kf + 2097152;
    bf16* tmpf = Vt + 2097152 * 8;
    bf16* Wof = tmpf + 16777216;
    bf16* Wvf = Wof + 32768;
    float* out = (float*)d_out;

    prep<<<160, 256, 0, stream>>>(Wq, Wk, freqs, Wo, Wv, Fqb, Fkb, Wof, Wvf);
    encvp<<<2048, 256, 0, stream>>>(q_atoms, q_logw, k_atoms, k_logw,
                                    Fqb, Fkb, qf, kf,
                                    v_atoms, Wvf, Vt);
    attn_kern<<<1024, 512, 0, stream>>>(qf, kf, Vt, tmpf);
    finalize<<<CB * CS / 8, 256, 0, stream>>>(tmpf, Wof, Ww, q_logw, out);
}